// Round 1
// baseline (2301.887 us; speedup 1.0000x reference)
//
#include <hip/hip_runtime.h>

constexpr int NN = 100000;
constexpr int NE = 1600000;
constexpr int NG = 64;
constexpr int H  = 128;

__global__ void k_init_deg(float* deg, int n) {
  int i = blockIdx.x * blockDim.x + threadIdx.x;
  if (i < n) deg[i] = 1.0f;   // self-loop
}

__global__ void k_deg_accum(const int* __restrict__ ei, float* deg, int ne) {
  int stride = gridDim.x * blockDim.x;
  for (int e = blockIdx.x * blockDim.x + threadIdx.x; e < ne; e += stride) {
    atomicAdd(&deg[ei[ne + e]], 1.0f);
  }
}

__global__ void k_rsqrt(float* deg, int n) {
  int i = blockIdx.x * blockDim.x + threadIdx.x;
  if (i < n) deg[i] = rsqrtf(deg[i]);
}

// layer1: x[N,10] @ W[10,128] -> h; acc initialized with self-loop term h*dis^2
__global__ void k_mm10(const float* __restrict__ x, const float* __restrict__ W,
                       const float* __restrict__ dis, float* __restrict__ h,
                       float* __restrict__ acc, int n) {
  int node = blockIdx.x;
  if (node >= n) return;
  __shared__ float xs[10];
  int m = threadIdx.x;
  if (m < 10) xs[m] = x[node * 10 + m];
  __syncthreads();
  float s = 0.f;
#pragma unroll
  for (int k = 0; k < 10; ++k) s += xs[k] * W[k * H + m];
  float d = dis[node];
  h[node * H + m] = s;
  acc[node * H + m] = s * d * d;
}

// layers 2/3: xin[N,128] @ W[128,128] -> h; acc = h*dis^2
// 256 threads, 8 nodes/block; thread computes 4 node-outputs for one column m.
__global__ void k_mm128(const float* __restrict__ xin, const float* __restrict__ W,
                        const float* __restrict__ dis, float* __restrict__ h,
                        float* __restrict__ acc, int n) {
  __shared__ float xs[8][H];
  int t = threadIdx.x;
  int n0 = blockIdx.x * 8;
#pragma unroll
  for (int i = 0; i < 4; ++i) {
    int idx = t + i * 256;
    int nn = idx >> 7, k = idx & 127;
    int node = n0 + nn;
    xs[nn][k] = (node < n) ? xin[node * H + k] : 0.f;
  }
  __syncthreads();
  int m = t & 127, ng = t >> 7;
  float a0 = 0, a1 = 0, a2 = 0, a3 = 0;
  for (int k = 0; k < H; ++k) {
    float w = W[k * H + m];
    a0 += xs[ng * 4 + 0][k] * w;
    a1 += xs[ng * 4 + 1][k] * w;
    a2 += xs[ng * 4 + 2][k] * w;
    a3 += xs[ng * 4 + 3][k] * w;
  }
  float av[4] = {a0, a1, a2, a3};
#pragma unroll
  for (int i = 0; i < 4; ++i) {
    int node = n0 + ng * 4 + i;
    if (node < n) {
      float d = dis[node];
      h[node * H + m] = av[i];
      acc[node * H + m] = av[i] * d * d;
    }
  }
}

// edge scatter: acc[dst] += dis[src]*dis[dst]*h[src]; 128 lanes = 128 features
__global__ void k_scatter(const int* __restrict__ ei, const float* __restrict__ dis,
                          const float* __restrict__ h, float* __restrict__ acc, int ne) {
  int m = threadIdx.x & 127;
  int eo = threadIdx.x >> 7;
  int estride = gridDim.x * 2;
  for (int e = blockIdx.x * 2 + eo; e < ne; e += estride) {
    int s = ei[e];
    int d = ei[ne + e];
    float nrm = dis[s] * dis[d];
    atomicAdd(&acc[d * H + m], nrm * h[s * H + m]);
  }
}

__global__ void k_bias_relu(const float* __restrict__ acc, const float* __restrict__ b,
                            float* __restrict__ xout, int total) {
  int i = blockIdx.x * blockDim.x + threadIdx.x;
  if (i < total) {
    float v = acc[i] + b[i & 127];
    xout[i] = v > 0.f ? v : 0.f;
  }
}

__global__ void k_zero_pool(float* pool, float* cnt) {
  int i = blockIdx.x * blockDim.x + threadIdx.x;
  if (i < NG * H) pool[i] = 0.f;
  if (i < NG) cnt[i] = 0.f;
}

// batch is sorted: run-length accumulate per thread, flush one atomic per graph boundary
__global__ void k_pool(const float* __restrict__ acc, const float* __restrict__ b3,
                       const int* __restrict__ batch, float* pool, float* cnt, int n) {
  int m = threadIdx.x;
  int n0 = blockIdx.x * 64;
  float run = 0.f, crun = 0.f;
  int curg = -1;
  float bm = b3[m];
  for (int i = 0; i < 64; ++i) {
    int node = n0 + i;
    if (node >= n) break;
    int g = batch[node];
    if (g != curg) {
      if (curg >= 0) {
        atomicAdd(&pool[curg * H + m], run);
        if (m == 0) atomicAdd(&cnt[curg], crun);
      }
      curg = g; run = 0.f; crun = 0.f;
    }
    run += acc[node * H + m] + bm;
    crun += 1.f;
  }
  if (curg >= 0) {
    atomicAdd(&pool[curg * H + m], run);
    if (m == 0) atomicAdd(&cnt[curg], crun);
  }
}

__global__ void k_out(const float* __restrict__ pool, const float* __restrict__ cnt,
                      const float* __restrict__ Wlin, const float* __restrict__ blin,
                      float* __restrict__ out) {
  int t = threadIdx.x;
  if (t >= NG * 3) return;
  int g = t / 3, c = t % 3;
  float invc = 1.f / fmaxf(cnt[g], 1.f);
  float s = 0.f;
  for (int m = 0; m < H; ++m) s += pool[g * H + m] * Wlin[m * 3 + c];
  out[t] = s * invc + blin[c];
}

extern "C" void kernel_launch(void* const* d_in, const int* in_sizes, int n_in,
                              void* d_out, int out_size, void* d_ws, size_t ws_size,
                              hipStream_t stream) {
  const float* x     = (const float*)d_in[0];
  const int*   ei    = (const int*)d_in[1];
  const int*   batch = (const int*)d_in[2];
  const float* W1    = (const float*)d_in[3];
  const float* b1    = (const float*)d_in[4];
  const float* W2    = (const float*)d_in[5];
  const float* b2    = (const float*)d_in[6];
  const float* W3    = (const float*)d_in[7];
  const float* b3    = (const float*)d_in[8];
  const float* Wlin  = (const float*)d_in[9];
  const float* blin  = (const float*)d_in[10];
  float* out = (float*)d_out;

  float* ws   = (float*)d_ws;
  float* dis  = ws;                       // NN
  float* h    = dis + NN;                 // NN*H
  float* acc  = h + (size_t)NN * H;       // NN*H
  float* xbuf = acc + (size_t)NN * H;     // NN*H
  float* pool = xbuf + (size_t)NN * H;    // NG*H
  float* cnt  = pool + NG * H;            // NG

  // degree / symmetric norm
  k_init_deg<<<(NN + 255) / 256, 256, 0, stream>>>(dis, NN);
  k_deg_accum<<<2048, 256, 0, stream>>>(ei, dis, NE);
  k_rsqrt<<<(NN + 255) / 256, 256, 0, stream>>>(dis, NN);
  k_zero_pool<<<(NG * H + 255) / 256, 256, 0, stream>>>(pool, cnt);

  // layer 1
  k_mm10<<<NN, 128, 0, stream>>>(x, W1, dis, h, acc, NN);
  k_scatter<<<16384, 256, 0, stream>>>(ei, dis, h, acc, NE);
  k_bias_relu<<<(NN * H + 255) / 256, 256, 0, stream>>>(acc, b1, xbuf, NN * H);

  // layer 2
  k_mm128<<<(NN + 7) / 8, 256, 0, stream>>>(xbuf, W2, dis, h, acc, NN);
  k_scatter<<<16384, 256, 0, stream>>>(ei, dis, h, acc, NE);
  k_bias_relu<<<(NN * H + 255) / 256, 256, 0, stream>>>(acc, b2, xbuf, NN * H);

  // layer 3
  k_mm128<<<(NN + 7) / 8, 256, 0, stream>>>(xbuf, W3, dis, h, acc, NN);
  k_scatter<<<16384, 256, 0, stream>>>(ei, dis, h, acc, NE);
  k_pool<<<(NN + 63) / 64, 128, 0, stream>>>(acc, b3, batch, pool, cnt, NN);

  k_out<<<1, 256, 0, stream>>>(pool, cnt, Wlin, blin, out);
}

// Round 2
// 1256.832 us; speedup vs baseline: 1.8315x; 1.8315x over previous
//
#include <hip/hip_runtime.h>

constexpr int NN = 100000;
constexpr int NE = 1600000;
constexpr int NG = 64;
constexpr int H  = 128;

// ---------- CSR build ----------

__global__ void k_zero_int(int* p, int n) {
  int i = blockIdx.x * blockDim.x + threadIdx.x;
  if (i < n) p[i] = 0;
}

__global__ void k_indeg(const int* __restrict__ ei, int* indeg, int ne) {
  int stride = gridDim.x * blockDim.x;
  for (int e = blockIdx.x * blockDim.x + threadIdx.x; e < ne; e += stride) {
    atomicAdd(&indeg[ei[ne + e]], 1);
  }
}

// single-block exclusive scan over indeg -> offs/cursor; also dis = rsqrt(indeg+1)
__global__ void k_scan(const int* __restrict__ indeg, int* __restrict__ offs,
                       int* __restrict__ cursor, float* __restrict__ dis, int n) {
  __shared__ int partial[1024];
  int t = threadIdx.x;
  const int chunk = (n + 1023) / 1024;
  int beg = t * chunk;
  int end = min(beg + chunk, n);
  int s = 0;
  for (int i = beg; i < end; ++i) s += indeg[i];
  partial[t] = s;
  __syncthreads();
  if (t == 0) {
    int run = 0;
    for (int i = 0; i < 1024; ++i) { int v = partial[i]; partial[i] = run; run += v; }
  }
  __syncthreads();
  int run = partial[t];
  for (int i = beg; i < end; ++i) {
    offs[i] = run;
    cursor[i] = run;
    dis[i] = rsqrtf((float)(indeg[i] + 1));
    run += indeg[i];
  }
  if (t == 1023) offs[n] = run;
}

__global__ void k_fill(const int* __restrict__ ei, int* cursor,
                       int* __restrict__ csr, int ne) {
  int stride = gridDim.x * blockDim.x;
  for (int e = blockIdx.x * blockDim.x + threadIdx.x; e < ne; e += stride) {
    int s = ei[e];
    int d = ei[ne + e];
    int pos = atomicAdd(&cursor[d], 1);
    csr[pos] = s;
  }
}

// ---------- dense layers ----------

__global__ void k_mm10(const float* __restrict__ x, const float* __restrict__ W,
                       float* __restrict__ h, int n) {
  int node = blockIdx.x;
  if (node >= n) return;
  __shared__ float xs[10];
  int m = threadIdx.x;
  if (m < 10) xs[m] = x[node * 10 + m];
  __syncthreads();
  float s = 0.f;
#pragma unroll
  for (int k = 0; k < 10; ++k) s += xs[k] * W[k * H + m];
  h[node * H + m] = s;
}

// xin[N,128] @ W[128,128] -> h; 256 threads, 8 nodes/block, 4 nodes/thread
__global__ void k_mm128(const float* __restrict__ xin, const float* __restrict__ W,
                        float* __restrict__ h, int n) {
  __shared__ float xs[8][H];
  int t = threadIdx.x;
  int n0 = blockIdx.x * 8;
#pragma unroll
  for (int i = 0; i < 4; ++i) {
    int idx = t + i * 256;
    int nn = idx >> 7, k = idx & 127;
    int node = n0 + nn;
    xs[nn][k] = (node < n) ? xin[node * H + k] : 0.f;
  }
  __syncthreads();
  int m = t & 127, ng = t >> 7;
  float a0 = 0, a1 = 0, a2 = 0, a3 = 0;
  for (int k = 0; k < H; ++k) {
    float w = W[k * H + m];
    a0 += xs[ng * 4 + 0][k] * w;
    a1 += xs[ng * 4 + 1][k] * w;
    a2 += xs[ng * 4 + 2][k] * w;
    a3 += xs[ng * 4 + 3][k] * w;
  }
  float av[4] = {a0, a1, a2, a3};
#pragma unroll
  for (int i = 0; i < 4; ++i) {
    int node = n0 + ng * 4 + i;
    if (node < n) h[node * H + m] = av[i];
  }
}

// ---------- gather (replaces atomic scatter) ----------
// out[d,m] = dis[d] * ( dis[d]*h[d,m] + sum_{s in N_in(d)} dis[s]*h[s,m] ) [+b][relu]
template <bool RELU, bool BIAS>
__global__ void k_gather(const int* __restrict__ offs, const int* __restrict__ csr,
                         const float* __restrict__ dis, const float* __restrict__ h,
                         const float* __restrict__ b, float* __restrict__ out, int n) {
  int m = threadIdx.x & 127;
  int node = blockIdx.x * 2 + (threadIdx.x >> 7);
  if (node >= n) return;
  float dd = dis[node];
  float sum = dd * h[node * H + m];
  int beg = offs[node], end = offs[node + 1];
  int e = beg;
  for (; e + 1 < end; e += 2) {
    int s0 = csr[e], s1 = csr[e + 1];
    float w0 = dis[s0], w1 = dis[s1];
    sum += w0 * h[s0 * H + m];
    sum += w1 * h[s1 * H + m];
  }
  if (e < end) {
    int s0 = csr[e];
    sum += dis[s0] * h[s0 * H + m];
  }
  float v = sum * dd;
  if (BIAS) v += b[m];
  if (RELU) v = fmaxf(v, 0.f);
  out[node * H + m] = v;
}

// ---------- pooling / output ----------

__global__ void k_zero_pool(float* pool, float* cnt) {
  int i = blockIdx.x * blockDim.x + threadIdx.x;
  if (i < NG * H) pool[i] = 0.f;
  if (i < NG) cnt[i] = 0.f;
}

__global__ void k_pool(const float* __restrict__ acc, const float* __restrict__ b3,
                       const int* __restrict__ batch, float* pool, float* cnt, int n) {
  int m = threadIdx.x;
  int n0 = blockIdx.x * 64;
  float run = 0.f, crun = 0.f;
  int curg = -1;
  float bm = b3[m];
  for (int i = 0; i < 64; ++i) {
    int node = n0 + i;
    if (node >= n) break;
    int g = batch[node];
    if (g != curg) {
      if (curg >= 0) {
        atomicAdd(&pool[curg * H + m], run);
        if (m == 0) atomicAdd(&cnt[curg], crun);
      }
      curg = g; run = 0.f; crun = 0.f;
    }
    run += acc[node * H + m] + bm;
    crun += 1.f;
  }
  if (curg >= 0) {
    atomicAdd(&pool[curg * H + m], run);
    if (m == 0) atomicAdd(&cnt[curg], crun);
  }
}

__global__ void k_out(const float* __restrict__ pool, const float* __restrict__ cnt,
                      const float* __restrict__ Wlin, const float* __restrict__ blin,
                      float* __restrict__ out) {
  int t = threadIdx.x;
  if (t >= NG * 3) return;
  int g = t / 3, c = t % 3;
  float invc = 1.f / fmaxf(cnt[g], 1.f);
  float s = 0.f;
  for (int m = 0; m < H; ++m) s += pool[g * H + m] * Wlin[m * 3 + c];
  out[t] = s * invc + blin[c];
}

extern "C" void kernel_launch(void* const* d_in, const int* in_sizes, int n_in,
                              void* d_out, int out_size, void* d_ws, size_t ws_size,
                              hipStream_t stream) {
  const float* x     = (const float*)d_in[0];
  const int*   ei    = (const int*)d_in[1];
  const int*   batch = (const int*)d_in[2];
  const float* W1    = (const float*)d_in[3];
  const float* b1    = (const float*)d_in[4];
  const float* W2    = (const float*)d_in[5];
  const float* b2    = (const float*)d_in[6];
  const float* W3    = (const float*)d_in[7];
  const float* b3    = (const float*)d_in[8];
  const float* Wlin  = (const float*)d_in[9];
  const float* blin  = (const float*)d_in[10];
  float* out = (float*)d_out;

  char* ws = (char*)d_ws;
  float* dis    = (float*)ws;                       ws += sizeof(float) * NN;
  float* h      = (float*)ws;                       ws += sizeof(float) * (size_t)NN * H;
  float* xbuf   = (float*)ws;                       ws += sizeof(float) * (size_t)NN * H;
  float* pool   = (float*)ws;                       ws += sizeof(float) * NG * H;
  float* cnt    = (float*)ws;                       ws += sizeof(float) * NG;
  int*   indeg  = (int*)ws;                         ws += sizeof(int) * NN;
  int*   offs   = (int*)ws;                         ws += sizeof(int) * (NN + 1);
  int*   cursor = (int*)ws;                         ws += sizeof(int) * NN;
  int*   csr    = (int*)ws;                         ws += sizeof(int) * NE;

  // CSR build (once; reused by all 3 layers)
  k_zero_int<<<(NN + 255) / 256, 256, 0, stream>>>(indeg, NN);
  k_indeg<<<2048, 256, 0, stream>>>(ei, indeg, NE);
  k_scan<<<1, 1024, 0, stream>>>(indeg, offs, cursor, dis, NN);
  k_fill<<<2048, 256, 0, stream>>>(ei, cursor, csr, NE);
  k_zero_pool<<<(NG * H + 255) / 256, 256, 0, stream>>>(pool, cnt);

  const int GATHER_GRID = (NN + 1) / 2;

  // layer 1
  k_mm10<<<NN, 128, 0, stream>>>(x, W1, h, NN);
  k_gather<true, true><<<GATHER_GRID, 256, 0, stream>>>(offs, csr, dis, h, b1, xbuf, NN);

  // layer 2
  k_mm128<<<(NN + 7) / 8, 256, 0, stream>>>(xbuf, W2, h, NN);
  k_gather<true, true><<<GATHER_GRID, 256, 0, stream>>>(offs, csr, dis, h, b2, xbuf, NN);

  // layer 3
  k_mm128<<<(NN + 7) / 8, 256, 0, stream>>>(xbuf, W3, h, NN);
  k_gather<false, false><<<GATHER_GRID, 256, 0, stream>>>(offs, csr, dis, h, nullptr, xbuf, NN);

  // pool + head
  k_pool<<<(NN + 63) / 64, 128, 0, stream>>>(xbuf, b3, batch, pool, cnt, NN);
  k_out<<<1, 256, 0, stream>>>(pool, cnt, Wlin, blin, out);
}

// Round 3
// 850.848 us; speedup vs baseline: 2.7054x; 1.4772x over previous
//
#include <hip/hip_runtime.h>

constexpr int NN = 100000;
constexpr int NE = 1600000;
constexpr int NG = 64;
constexpr int H  = 128;
constexpr int SCAN_CHUNK = 1024;
constexpr int NBLK = (NN + SCAN_CHUNK - 1) / SCAN_CHUNK;  // 98

// ---------- CSR build ----------

__global__ void k_zero_int(int* p, int n) {
  int i = blockIdx.x * blockDim.x + threadIdx.x;
  if (i < n) p[i] = 0;
}

__global__ void k_indeg(const int* __restrict__ ei, int* indeg, int ne) {
  int stride = gridDim.x * blockDim.x;
  for (int e = blockIdx.x * blockDim.x + threadIdx.x; e < ne; e += stride) {
    atomicAdd(&indeg[ei[ne + e]], 1);
  }
}

// pass 1: per-block (1024 elems) sums
__global__ void k_blocksum(const int* __restrict__ indeg, int* __restrict__ bsum, int n) {
  int t = threadIdx.x;
  int base = blockIdx.x * SCAN_CHUNK + t * 4;
  int s = 0;
  if (base + 3 < n) {
    int4 v = *(const int4*)&indeg[base];
    s = v.x + v.y + v.z + v.w;
  } else {
#pragma unroll
    for (int i = 0; i < 4; ++i) if (base + i < n) s += indeg[base + i];
  }
#pragma unroll
  for (int off = 32; off; off >>= 1) s += __shfl_down(s, off, 64);
  __shared__ int ws[4];
  if ((t & 63) == 0) ws[t >> 6] = s;
  __syncthreads();
  if (t == 0) bsum[blockIdx.x] = ws[0] + ws[1] + ws[2] + ws[3];
}

// pass 2: serial scan of 98 block sums (tiny)
__global__ void k_scanbsum(const int* __restrict__ bsum, int* __restrict__ boff,
                           int* __restrict__ offs, int nb, int n) {
  if (threadIdx.x == 0) {
    int run = 0;
    for (int i = 0; i < nb; ++i) { int v = bsum[i]; boff[i] = run; run += v; }
    offs[n] = run;
  }
}

// pass 3: block-local exclusive scan + emit offs/cursor/dis
__global__ void k_scanfinal(const int* __restrict__ indeg, const int* __restrict__ boff,
                            int* __restrict__ offs, int* __restrict__ cursor,
                            float* __restrict__ dis, int n) {
  int t = threadIdx.x;
  int base = blockIdx.x * SCAN_CHUNK + t * 4;
  int v[4];
  int s = 0;
  if (base + 3 < n) {
    int4 q = *(const int4*)&indeg[base];
    v[0] = q.x; v[1] = q.y; v[2] = q.z; v[3] = q.w;
  } else {
#pragma unroll
    for (int i = 0; i < 4; ++i) v[i] = (base + i < n) ? indeg[base + i] : 0;
  }
  s = v[0] + v[1] + v[2] + v[3];

  int lane = t & 63, w = t >> 6;
  int inc = s;
#pragma unroll
  for (int off = 1; off < 64; off <<= 1) {
    int y = __shfl_up(inc, off, 64);
    if (lane >= off) inc += y;
  }
  __shared__ int wsum[4];
  if (lane == 63) wsum[w] = inc;
  __syncthreads();
  int woff = 0;
  for (int i = 0; i < w; ++i) woff += wsum[i];
  int run = woff + (inc - s) + boff[blockIdx.x];

  if (base + 3 < n) {
    int4 ov; float4 dv;
    int r = run;
    ov.x = r; dv.x = rsqrtf((float)(v[0] + 1)); r += v[0];
    ov.y = r; dv.y = rsqrtf((float)(v[1] + 1)); r += v[1];
    ov.z = r; dv.z = rsqrtf((float)(v[2] + 1)); r += v[2];
    ov.w = r; dv.w = rsqrtf((float)(v[3] + 1)); r += v[3];
    *(int4*)&offs[base] = ov;
    *(int4*)&cursor[base] = ov;
    *(float4*)&dis[base] = dv;
  } else {
    int r = run;
#pragma unroll
    for (int i = 0; i < 4; ++i) {
      if (base + i < n) {
        offs[base + i] = r; cursor[base + i] = r;
        dis[base + i] = rsqrtf((float)(v[i] + 1));
        r += v[i];
      }
    }
  }
}

__global__ void k_fill(const int* __restrict__ ei, int* cursor,
                       int* __restrict__ csr, int ne) {
  int stride = gridDim.x * blockDim.x;
  for (int e = blockIdx.x * blockDim.x + threadIdx.x; e < ne; e += stride) {
    int s = ei[e];
    int d = ei[ne + e];
    int pos = atomicAdd(&cursor[d], 1);
    csr[pos] = s;
  }
}

// ---------- dense layers ----------

__global__ void k_mm10(const float* __restrict__ x, const float* __restrict__ W,
                       float* __restrict__ h, int n) {
  int node = blockIdx.x;
  if (node >= n) return;
  __shared__ float xs[10];
  int m = threadIdx.x;
  if (m < 10) xs[m] = x[node * 10 + m];
  __syncthreads();
  float s = 0.f;
#pragma unroll
  for (int k = 0; k < 10; ++k) s += xs[k] * W[k * H + m];
  h[node * H + m] = s;
}

__global__ void k_mm128(const float* __restrict__ xin, const float* __restrict__ W,
                        float* __restrict__ h, int n) {
  __shared__ float xs[8][H];
  int t = threadIdx.x;
  int n0 = blockIdx.x * 8;
#pragma unroll
  for (int i = 0; i < 4; ++i) {
    int idx = t + i * 256;
    int nn = idx >> 7, k = idx & 127;
    int node = n0 + nn;
    xs[nn][k] = (node < n) ? xin[node * H + k] : 0.f;
  }
  __syncthreads();
  int m = t & 127, ng = t >> 7;
  float a0 = 0, a1 = 0, a2 = 0, a3 = 0;
  for (int k = 0; k < H; ++k) {
    float w = W[k * H + m];
    a0 += xs[ng * 4 + 0][k] * w;
    a1 += xs[ng * 4 + 1][k] * w;
    a2 += xs[ng * 4 + 2][k] * w;
    a3 += xs[ng * 4 + 3][k] * w;
  }
  float av[4] = {a0, a1, a2, a3};
#pragma unroll
  for (int i = 0; i < 4; ++i) {
    int node = n0 + ng * 4 + i;
    if (node < n) h[node * H + m] = av[i];
  }
}

// ---------- gather ----------
template <bool RELU, bool BIAS>
__global__ void k_gather(const int* __restrict__ offs, const int* __restrict__ csr,
                         const float* __restrict__ dis, const float* __restrict__ h,
                         const float* __restrict__ b, float* __restrict__ out, int n) {
  int m = threadIdx.x & 127;
  int node = blockIdx.x * 2 + (threadIdx.x >> 7);
  if (node >= n) return;
  float dd = dis[node];
  float sum = dd * h[node * H + m];
  int beg = offs[node], end = offs[node + 1];
  int e = beg;
  for (; e + 3 < end; e += 4) {
    int s0 = csr[e], s1 = csr[e + 1], s2 = csr[e + 2], s3 = csr[e + 3];
    float w0 = dis[s0], w1 = dis[s1], w2 = dis[s2], w3 = dis[s3];
    float h0 = h[s0 * H + m], h1 = h[s1 * H + m];
    float h2 = h[s2 * H + m], h3 = h[s3 * H + m];
    sum += w0 * h0 + w1 * h1 + w2 * h2 + w3 * h3;
  }
  for (; e < end; ++e) {
    int s0 = csr[e];
    sum += dis[s0] * h[s0 * H + m];
  }
  float v = sum * dd;
  if (BIAS) v += b[m];
  if (RELU) v = fmaxf(v, 0.f);
  out[node * H + m] = v;
}

// ---------- pooling / output ----------

__global__ void k_zero_pool(float* pool, float* cnt) {
  int i = blockIdx.x * blockDim.x + threadIdx.x;
  if (i < NG * H) pool[i] = 0.f;
  if (i < NG) cnt[i] = 0.f;
}

__global__ void k_pool(const float* __restrict__ acc, const float* __restrict__ b3,
                       const int* __restrict__ batch, float* pool, float* cnt, int n) {
  int m = threadIdx.x;
  int n0 = blockIdx.x * 64;
  float run = 0.f, crun = 0.f;
  int curg = -1;
  float bm = b3[m];
  for (int i = 0; i < 64; ++i) {
    int node = n0 + i;
    if (node >= n) break;
    int g = batch[node];
    if (g != curg) {
      if (curg >= 0) {
        atomicAdd(&pool[curg * H + m], run);
        if (m == 0) atomicAdd(&cnt[curg], crun);
      }
      curg = g; run = 0.f; crun = 0.f;
    }
    run += acc[node * H + m] + bm;
    crun += 1.f;
  }
  if (curg >= 0) {
    atomicAdd(&pool[curg * H + m], run);
    if (m == 0) atomicAdd(&cnt[curg], crun);
  }
}

__global__ void k_out(const float* __restrict__ pool, const float* __restrict__ cnt,
                      const float* __restrict__ Wlin, const float* __restrict__ blin,
                      float* __restrict__ out) {
  int t = threadIdx.x;
  if (t >= NG * 3) return;
  int g = t / 3, c = t % 3;
  float invc = 1.f / fmaxf(cnt[g], 1.f);
  float s = 0.f;
  for (int m = 0; m < H; ++m) s += pool[g * H + m] * Wlin[m * 3 + c];
  out[t] = s * invc + blin[c];
}

extern "C" void kernel_launch(void* const* d_in, const int* in_sizes, int n_in,
                              void* d_out, int out_size, void* d_ws, size_t ws_size,
                              hipStream_t stream) {
  const float* x     = (const float*)d_in[0];
  const int*   ei    = (const int*)d_in[1];
  const int*   batch = (const int*)d_in[2];
  const float* W1    = (const float*)d_in[3];
  const float* b1    = (const float*)d_in[4];
  const float* W2    = (const float*)d_in[5];
  const float* b2    = (const float*)d_in[6];
  const float* W3    = (const float*)d_in[7];
  const float* b3    = (const float*)d_in[8];
  const float* Wlin  = (const float*)d_in[9];
  const float* blin  = (const float*)d_in[10];
  float* out = (float*)d_out;

  char* ws = (char*)d_ws;
  float* dis    = (float*)ws;  ws += sizeof(float) * NN;
  float* h      = (float*)ws;  ws += sizeof(float) * (size_t)NN * H;
  float* xbuf   = (float*)ws;  ws += sizeof(float) * (size_t)NN * H;
  float* pool   = (float*)ws;  ws += sizeof(float) * NG * H;
  float* cnt    = (float*)ws;  ws += sizeof(float) * NG;
  int*   indeg  = (int*)ws;    ws += sizeof(int) * NN;
  int*   offs   = (int*)ws;    ws += sizeof(int) * (NN + 1);
  int*   cursor = (int*)ws;    ws += sizeof(int) * NN;
  int*   csr    = (int*)ws;    ws += sizeof(int) * NE;
  int*   bsum   = (int*)ws;    ws += sizeof(int) * NBLK;
  int*   boff   = (int*)ws;    ws += sizeof(int) * NBLK;

  // CSR build (parallel scan)
  k_zero_int<<<(NN + 255) / 256, 256, 0, stream>>>(indeg, NN);
  k_indeg<<<2048, 256, 0, stream>>>(ei, indeg, NE);
  k_blocksum<<<NBLK, 256, 0, stream>>>(indeg, bsum, NN);
  k_scanbsum<<<1, 64, 0, stream>>>(bsum, boff, offs, NBLK, NN);
  k_scanfinal<<<NBLK, 256, 0, stream>>>(indeg, boff, offs, cursor, dis, NN);
  k_fill<<<2048, 256, 0, stream>>>(ei, cursor, csr, NE);
  k_zero_pool<<<(NG * H + 255) / 256, 256, 0, stream>>>(pool, cnt);

  const int GATHER_GRID = (NN + 1) / 2;

  // layer 1
  k_mm10<<<NN, 128, 0, stream>>>(x, W1, h, NN);
  k_gather<true, true><<<GATHER_GRID, 256, 0, stream>>>(offs, csr, dis, h, b1, xbuf, NN);

  // layer 2
  k_mm128<<<(NN + 7) / 8, 256, 0, stream>>>(xbuf, W2, h, NN);
  k_gather<true, true><<<GATHER_GRID, 256, 0, stream>>>(offs, csr, dis, h, b2, xbuf, NN);

  // layer 3
  k_mm128<<<(NN + 7) / 8, 256, 0, stream>>>(xbuf, W3, h, NN);
  k_gather<false, false><<<GATHER_GRID, 256, 0, stream>>>(offs, csr, dis, h, nullptr, xbuf, NN);

  // pool + head
  k_pool<<<(NN + 63) / 64, 128, 0, stream>>>(xbuf, b3, batch, pool, cnt, NN);
  k_out<<<1, 256, 0, stream>>>(pool, cnt, Wlin, blin, out);
}

// Round 4
// 766.199 us; speedup vs baseline: 3.0043x; 1.1105x over previous
//
#include <hip/hip_runtime.h>

constexpr int NN = 100000;
constexpr int NE = 1600000;
constexpr int NG = 64;
constexpr int H  = 128;
constexpr int SCAN_CHUNK = 1024;
constexpr int NBLK = (NN + SCAN_CHUNK - 1) / SCAN_CHUNK;  // 98

// ---------- CSR build ----------

__global__ void k_zero_int(int* p, int n) {
  int i = blockIdx.x * blockDim.x + threadIdx.x;
  if (i < n) p[i] = 0;
}

__global__ void k_indeg(const int* __restrict__ ei, int* indeg, int ne) {
  int stride = gridDim.x * blockDim.x;
  for (int e = blockIdx.x * blockDim.x + threadIdx.x; e < ne; e += stride) {
    atomicAdd(&indeg[ei[ne + e]], 1);
  }
}

__global__ void k_blocksum(const int* __restrict__ indeg, int* __restrict__ bsum, int n) {
  int t = threadIdx.x;
  int base = blockIdx.x * SCAN_CHUNK + t * 4;
  int s = 0;
  if (base + 3 < n) {
    int4 v = *(const int4*)&indeg[base];
    s = v.x + v.y + v.z + v.w;
  } else {
#pragma unroll
    for (int i = 0; i < 4; ++i) if (base + i < n) s += indeg[base + i];
  }
#pragma unroll
  for (int off = 32; off; off >>= 1) s += __shfl_down(s, off, 64);
  __shared__ int ws[4];
  if ((t & 63) == 0) ws[t >> 6] = s;
  __syncthreads();
  if (t == 0) bsum[blockIdx.x] = ws[0] + ws[1] + ws[2] + ws[3];
}

__global__ void k_scanbsum(const int* __restrict__ bsum, int* __restrict__ boff,
                           int* __restrict__ offs, int nb, int n) {
  if (threadIdx.x == 0) {
    int run = 0;
    for (int i = 0; i < nb; ++i) { int v = bsum[i]; boff[i] = run; run += v; }
    offs[n] = run;
  }
}

__global__ void k_scanfinal(const int* __restrict__ indeg, const int* __restrict__ boff,
                            int* __restrict__ offs, int* __restrict__ cursor,
                            float* __restrict__ dis, int n) {
  int t = threadIdx.x;
  int base = blockIdx.x * SCAN_CHUNK + t * 4;
  int v[4];
  int s = 0;
  if (base + 3 < n) {
    int4 q = *(const int4*)&indeg[base];
    v[0] = q.x; v[1] = q.y; v[2] = q.z; v[3] = q.w;
  } else {
#pragma unroll
    for (int i = 0; i < 4; ++i) v[i] = (base + i < n) ? indeg[base + i] : 0;
  }
  s = v[0] + v[1] + v[2] + v[3];

  int lane = t & 63, w = t >> 6;
  int inc = s;
#pragma unroll
  for (int off = 1; off < 64; off <<= 1) {
    int y = __shfl_up(inc, off, 64);
    if (lane >= off) inc += y;
  }
  __shared__ int wsum[4];
  if (lane == 63) wsum[w] = inc;
  __syncthreads();
  int woff = 0;
  for (int i = 0; i < w; ++i) woff += wsum[i];
  int run = woff + (inc - s) + boff[blockIdx.x];

  if (base + 3 < n) {
    int4 ov; float4 dv;
    int r = run;
    ov.x = r; dv.x = rsqrtf((float)(v[0] + 1)); r += v[0];
    ov.y = r; dv.y = rsqrtf((float)(v[1] + 1)); r += v[1];
    ov.z = r; dv.z = rsqrtf((float)(v[2] + 1)); r += v[2];
    ov.w = r; dv.w = rsqrtf((float)(v[3] + 1)); r += v[3];
    *(int4*)&offs[base] = ov;
    *(int4*)&cursor[base] = ov;
    *(float4*)&dis[base] = dv;
  } else {
    int r = run;
#pragma unroll
    for (int i = 0; i < 4; ++i) {
      if (base + i < n) {
        offs[base + i] = r; cursor[base + i] = r;
        dis[base + i] = rsqrtf((float)(v[i] + 1));
        r += v[i];
      }
    }
  }
}

__global__ void k_fill(const int* __restrict__ ei, int* cursor,
                       int* __restrict__ csr, int ne) {
  int stride = gridDim.x * blockDim.x;
  for (int e = blockIdx.x * blockDim.x + threadIdx.x; e < ne; e += stride) {
    int s = ei[e];
    int d = ei[ne + e];
    int pos = atomicAdd(&cursor[d], 1);
    csr[pos] = s;
  }
}

// ---------- dense layers (write hs = (x@W) * dis) ----------

__global__ void k_mm10(const float* __restrict__ x, const float* __restrict__ W,
                       const float* __restrict__ dis, float* __restrict__ hs, int n) {
  int node = blockIdx.x;
  if (node >= n) return;
  __shared__ float xs[10];
  int m = threadIdx.x;
  if (m < 10) xs[m] = x[node * 10 + m];
  __syncthreads();
  float s = 0.f;
#pragma unroll
  for (int k = 0; k < 10; ++k) s += xs[k] * W[k * H + m];
  hs[node * H + m] = s * dis[node];
}

// xin[N,128] @ W[128,128] -> hs; 256 threads, 32 nodes/block,
// thread = (m4 = t&31 feature-quad, ng = t>>5 owning 4 nodes), float4 math.
__global__ void k_mm128(const float* __restrict__ xin, const float* __restrict__ W,
                        const float* __restrict__ dis, float* __restrict__ hs, int n) {
  __shared__ float xs[32][H];
  int t = threadIdx.x;
  int n0 = blockIdx.x * 32;
#pragma unroll
  for (int i = 0; i < 4; ++i) {
    int f4 = i * 256 + t;          // 0..1023 float4 slots
    int row = f4 >> 5, c4 = f4 & 31;
    float4 v = *(const float4*)&xin[(n0 + row) * H + c4 * 4];
    *(float4*)&xs[row][c4 * 4] = v;
  }
  __syncthreads();
  int m4 = t & 31, ng = t >> 5;
  float4 a0 = {0,0,0,0}, a1 = {0,0,0,0}, a2 = {0,0,0,0}, a3 = {0,0,0,0};
  const float4* W4 = (const float4*)W;
#pragma unroll 4
  for (int k = 0; k < H; ++k) {
    float4 w = W4[k * 32 + m4];
    float x0 = xs[ng * 4 + 0][k];
    float x1 = xs[ng * 4 + 1][k];
    float x2 = xs[ng * 4 + 2][k];
    float x3 = xs[ng * 4 + 3][k];
    a0.x += w.x * x0; a0.y += w.y * x0; a0.z += w.z * x0; a0.w += w.w * x0;
    a1.x += w.x * x1; a1.y += w.y * x1; a1.z += w.z * x1; a1.w += w.w * x1;
    a2.x += w.x * x2; a2.y += w.y * x2; a2.z += w.z * x2; a2.w += w.w * x2;
    a3.x += w.x * x3; a3.y += w.y * x3; a3.z += w.z * x3; a3.w += w.w * x3;
  }
  float4 av[4] = {a0, a1, a2, a3};
#pragma unroll
  for (int j = 0; j < 4; ++j) {
    int node = n0 + ng * 4 + j;
    if (node < n) {
      float d = dis[node];
      float4 o;
      o.x = av[j].x * d; o.y = av[j].y * d; o.z = av[j].z * d; o.w = av[j].w * d;
      *(float4*)&hs[node * H + m4 * 4] = o;
    }
  }
}

// ---------- gather: one node per wave, float2 per lane ----------
// out[d] = dis[d] * ( hs[d] + sum_{s in N_in(d)} hs[s] ) [+b][relu]
template <bool RELU, bool BIAS>
__global__ void k_gather(const int* __restrict__ offs, const int* __restrict__ csr,
                         const float* __restrict__ dis, const float2* __restrict__ hs,
                         const float* __restrict__ b, float2* __restrict__ out, int n) {
  int node = (blockIdx.x * blockDim.x + threadIdx.x) >> 6;
  int lane = threadIdx.x & 63;
  if (node >= n) return;
  float2 self = hs[node * 64 + lane];
  float sx = self.x, sy = self.y;
  float tx = 0.f, ty = 0.f;
  int beg = offs[node], end = offs[node + 1];
  int e = beg;
  for (; e + 3 < end; e += 4) {
    int s0 = csr[e], s1 = csr[e + 1], s2 = csr[e + 2], s3 = csr[e + 3];
    float2 v0 = hs[s0 * 64 + lane];
    float2 v1 = hs[s1 * 64 + lane];
    float2 v2 = hs[s2 * 64 + lane];
    float2 v3 = hs[s3 * 64 + lane];
    sx += v0.x + v1.x; tx += v2.x + v3.x;
    sy += v0.y + v1.y; ty += v2.y + v3.y;
  }
  for (; e < end; ++e) {
    int s0 = csr[e];
    float2 v0 = hs[s0 * 64 + lane];
    sx += v0.x; sy += v0.y;
  }
  float dd = dis[node];
  float vx = (sx + tx) * dd, vy = (sy + ty) * dd;
  if (BIAS) {
    const float2* b2 = (const float2*)b;
    float2 bb = b2[lane];
    vx += bb.x; vy += bb.y;
  }
  if (RELU) { vx = fmaxf(vx, 0.f); vy = fmaxf(vy, 0.f); }
  float2 o; o.x = vx; o.y = vy;
  out[node * 64 + lane] = o;
}

// ---------- pooling / output ----------

__global__ void k_zero_pool(float* pool, float* cnt) {
  int i = blockIdx.x * blockDim.x + threadIdx.x;
  if (i < NG * H) pool[i] = 0.f;
  if (i < NG) cnt[i] = 0.f;
}

__global__ void k_pool(const float* __restrict__ acc, const float* __restrict__ b3,
                       const int* __restrict__ batch, float* pool, float* cnt, int n) {
  int m = threadIdx.x;
  int n0 = blockIdx.x * 64;
  float run = 0.f, crun = 0.f;
  int curg = -1;
  float bm = b3[m];
  for (int i = 0; i < 64; ++i) {
    int node = n0 + i;
    if (node >= n) break;
    int g = batch[node];
    if (g != curg) {
      if (curg >= 0) {
        atomicAdd(&pool[curg * H + m], run);
        if (m == 0) atomicAdd(&cnt[curg], crun);
      }
      curg = g; run = 0.f; crun = 0.f;
    }
    run += acc[node * H + m] + bm;
    crun += 1.f;
  }
  if (curg >= 0) {
    atomicAdd(&pool[curg * H + m], run);
    if (m == 0) atomicAdd(&cnt[curg], crun);
  }
}

__global__ void k_out(const float* __restrict__ pool, const float* __restrict__ cnt,
                      const float* __restrict__ Wlin, const float* __restrict__ blin,
                      float* __restrict__ out) {
  int t = threadIdx.x;
  if (t >= NG * 3) return;
  int g = t / 3, c = t % 3;
  float invc = 1.f / fmaxf(cnt[g], 1.f);
  float s = 0.f;
  for (int m = 0; m < H; ++m) s += pool[g * H + m] * Wlin[m * 3 + c];
  out[t] = s * invc + blin[c];
}

extern "C" void kernel_launch(void* const* d_in, const int* in_sizes, int n_in,
                              void* d_out, int out_size, void* d_ws, size_t ws_size,
                              hipStream_t stream) {
  const float* x     = (const float*)d_in[0];
  const int*   ei    = (const int*)d_in[1];
  const int*   batch = (const int*)d_in[2];
  const float* W1    = (const float*)d_in[3];
  const float* b1    = (const float*)d_in[4];
  const float* W2    = (const float*)d_in[5];
  const float* b2    = (const float*)d_in[6];
  const float* W3    = (const float*)d_in[7];
  const float* b3    = (const float*)d_in[8];
  const float* Wlin  = (const float*)d_in[9];
  const float* blin  = (const float*)d_in[10];
  float* out = (float*)d_out;

  char* ws = (char*)d_ws;
  float* dis    = (float*)ws;  ws += sizeof(float) * NN;
  float* hs     = (float*)ws;  ws += sizeof(float) * (size_t)NN * H;
  float* xbuf   = (float*)ws;  ws += sizeof(float) * (size_t)NN * H;
  float* pool   = (float*)ws;  ws += sizeof(float) * NG * H;
  float* cnt    = (float*)ws;  ws += sizeof(float) * NG;
  int*   indeg  = (int*)ws;    ws += sizeof(int) * NN;
  int*   offs   = (int*)ws;    ws += sizeof(int) * (NN + 1);
  int*   cursor = (int*)ws;    ws += sizeof(int) * NN;
  int*   csr    = (int*)ws;    ws += sizeof(int) * NE;
  int*   bsum   = (int*)ws;    ws += sizeof(int) * NBLK;
  int*   boff   = (int*)ws;    ws += sizeof(int) * NBLK;

  // CSR build (parallel scan)
  k_zero_int<<<(NN + 255) / 256, 256, 0, stream>>>(indeg, NN);
  k_indeg<<<2048, 256, 0, stream>>>(ei, indeg, NE);
  k_blocksum<<<NBLK, 256, 0, stream>>>(indeg, bsum, NN);
  k_scanbsum<<<1, 64, 0, stream>>>(bsum, boff, offs, NBLK, NN);
  k_scanfinal<<<NBLK, 256, 0, stream>>>(indeg, boff, offs, cursor, dis, NN);
  k_fill<<<2048, 256, 0, stream>>>(ei, cursor, csr, NE);
  k_zero_pool<<<(NG * H + 255) / 256, 256, 0, stream>>>(pool, cnt);

  const int GATHER_GRID = (NN + 3) / 4;   // 4 nodes/block (1 per wave)

  // layer 1
  k_mm10<<<NN, 128, 0, stream>>>(x, W1, dis, hs, NN);
  k_gather<true, true><<<GATHER_GRID, 256, 0, stream>>>(
      offs, csr, dis, (const float2*)hs, b1, (float2*)xbuf, NN);

  // layer 2
  k_mm128<<<(NN + 31) / 32, 256, 0, stream>>>(xbuf, W2, dis, hs, NN);
  k_gather<true, true><<<GATHER_GRID, 256, 0, stream>>>(
      offs, csr, dis, (const float2*)hs, b2, (float2*)xbuf, NN);

  // layer 3
  k_mm128<<<(NN + 31) / 32, 256, 0, stream>>>(xbuf, W3, dis, hs, NN);
  k_gather<false, false><<<GATHER_GRID, 256, 0, stream>>>(
      offs, csr, dis, (const float2*)hs, nullptr, (float2*)xbuf, NN);

  // pool + head
  k_pool<<<(NN + 63) / 64, 128, 0, stream>>>(xbuf, b3, batch, pool, cnt, NN);
  k_out<<<1, 256, 0, stream>>>(pool, cnt, Wlin, blin, out);
}

// Round 5
// 521.132 us; speedup vs baseline: 4.4171x; 1.4703x over previous
//
#include <hip/hip_runtime.h>

constexpr int NN = 100000;
constexpr int NE = 1600000;
constexpr int NG = 64;
constexpr int H  = 128;
constexpr int SCAN_CHUNK = 1024;
constexpr int NBLK = (NN + SCAN_CHUNK - 1) / SCAN_CHUNK;  // 98

// ---------- bf16 helpers ----------
__device__ __forceinline__ float bf_lo(unsigned v) { return __uint_as_float(v << 16); }
__device__ __forceinline__ float bf_hi(unsigned v) { return __uint_as_float(v & 0xffff0000u); }
__device__ __forceinline__ unsigned bf_pack(float a, float b) {  // RTNE
  unsigned ua = __float_as_uint(a);
  unsigned ub = __float_as_uint(b);
  ua += 0x7fffu + ((ua >> 16) & 1u);
  ub += 0x7fffu + ((ub >> 16) & 1u);
  return (ua >> 16) | (ub & 0xffff0000u);
}

// ---------- CSR build ----------

__global__ void k_zero_int(int* p, int n) {
  int i = blockIdx.x * blockDim.x + threadIdx.x;
  if (i < n) p[i] = 0;
}

// indeg histogram; atomicAdd's return value IS the edge's rank among same-dst edges
__global__ void k_indeg_rank(const int* __restrict__ ei, int* indeg,
                             int* __restrict__ rank, int ne) {
  int stride = gridDim.x * blockDim.x;
  for (int e = blockIdx.x * blockDim.x + threadIdx.x; e < ne; e += stride) {
    rank[e] = atomicAdd(&indeg[ei[ne + e]], 1);
  }
}

__global__ void k_blocksum(const int* __restrict__ indeg, int* __restrict__ bsum, int n) {
  int t = threadIdx.x;
  int base = blockIdx.x * SCAN_CHUNK + t * 4;
  int s = 0;
  if (base + 3 < n) {
    int4 v = *(const int4*)&indeg[base];
    s = v.x + v.y + v.z + v.w;
  } else {
#pragma unroll
    for (int i = 0; i < 4; ++i) if (base + i < n) s += indeg[base + i];
  }
#pragma unroll
  for (int off = 32; off; off >>= 1) s += __shfl_down(s, off, 64);
  __shared__ int ws[4];
  if ((t & 63) == 0) ws[t >> 6] = s;
  __syncthreads();
  if (t == 0) bsum[blockIdx.x] = ws[0] + ws[1] + ws[2] + ws[3];
}

__global__ void k_scanbsum(const int* __restrict__ bsum, int* __restrict__ boff,
                           int* __restrict__ offs, int nb, int n) {
  if (threadIdx.x == 0) {
    int run = 0;
    for (int i = 0; i < nb; ++i) { int v = bsum[i]; boff[i] = run; run += v; }
    offs[n] = run;
  }
}

__global__ void k_scanfinal(const int* __restrict__ indeg, const int* __restrict__ boff,
                            int* __restrict__ offs, float* __restrict__ dis, int n) {
  int t = threadIdx.x;
  int base = blockIdx.x * SCAN_CHUNK + t * 4;
  int v[4];
  int s = 0;
  if (base + 3 < n) {
    int4 q = *(const int4*)&indeg[base];
    v[0] = q.x; v[1] = q.y; v[2] = q.z; v[3] = q.w;
  } else {
#pragma unroll
    for (int i = 0; i < 4; ++i) v[i] = (base + i < n) ? indeg[base + i] : 0;
  }
  s = v[0] + v[1] + v[2] + v[3];

  int lane = t & 63, w = t >> 6;
  int inc = s;
#pragma unroll
  for (int off = 1; off < 64; off <<= 1) {
    int y = __shfl_up(inc, off, 64);
    if (lane >= off) inc += y;
  }
  __shared__ int wsum[4];
  if (lane == 63) wsum[w] = inc;
  __syncthreads();
  int woff = 0;
  for (int i = 0; i < w; ++i) woff += wsum[i];
  int run = woff + (inc - s) + boff[blockIdx.x];

  if (base + 3 < n) {
    int4 ov; float4 dv;
    int r = run;
    ov.x = r; dv.x = rsqrtf((float)(v[0] + 1)); r += v[0];
    ov.y = r; dv.y = rsqrtf((float)(v[1] + 1)); r += v[1];
    ov.z = r; dv.z = rsqrtf((float)(v[2] + 1)); r += v[2];
    ov.w = r; dv.w = rsqrtf((float)(v[3] + 1)); r += v[3];
    *(int4*)&offs[base] = ov;
    *(float4*)&dis[base] = dv;
  } else {
    int r = run;
#pragma unroll
    for (int i = 0; i < 4; ++i) {
      if (base + i < n) {
        offs[base + i] = r;
        dis[base + i] = rsqrtf((float)(v[i] + 1));
        r += v[i];
      }
    }
  }
}

// no atomic: position = offs[dst] + rank
__global__ void k_fill(const int* __restrict__ ei, const int* __restrict__ offs,
                       const int* __restrict__ rank, int* __restrict__ csr, int ne) {
  int stride = gridDim.x * blockDim.x;
  for (int e = blockIdx.x * blockDim.x + threadIdx.x; e < ne; e += stride) {
    int s = ei[e];
    int d = ei[ne + e];
    csr[offs[d] + rank[e]] = s;
  }
}

// ---------- dense layers (write hs = (x@W) * dis, bf16) ----------

__global__ void k_mm10(const float* __restrict__ x, const float* __restrict__ W,
                       const float* __restrict__ dis, ushort* __restrict__ hs, int n) {
  int node = blockIdx.x;
  if (node >= n) return;
  __shared__ float xs[10];
  int m = threadIdx.x;
  if (m < 10) xs[m] = x[node * 10 + m];
  __syncthreads();
  float s = 0.f;
#pragma unroll
  for (int k = 0; k < 10; ++k) s += xs[k] * W[k * H + m];
  float v = s * dis[node];
  unsigned u = __float_as_uint(v);
  u += 0x7fffu + ((u >> 16) & 1u);
  hs[node * H + m] = (ushort)(u >> 16);
}

// xin[N,128] @ W[128,128] -> hs(bf16); 256 threads, 32 nodes/block, float4 math
__global__ void k_mm128(const float* __restrict__ xin, const float* __restrict__ W,
                        const float* __restrict__ dis, unsigned* __restrict__ hs, int n) {
  __shared__ float xs[32][H];
  int t = threadIdx.x;
  int n0 = blockIdx.x * 32;
#pragma unroll
  for (int i = 0; i < 4; ++i) {
    int f4 = i * 256 + t;          // 0..1023 float4 slots
    int row = f4 >> 5, c4 = f4 & 31;
    float4 v = *(const float4*)&xin[(n0 + row) * H + c4 * 4];
    *(float4*)&xs[row][c4 * 4] = v;
  }
  __syncthreads();
  int m4 = t & 31, ng = t >> 5;
  float4 a0 = {0,0,0,0}, a1 = {0,0,0,0}, a2 = {0,0,0,0}, a3 = {0,0,0,0};
  const float4* W4 = (const float4*)W;
#pragma unroll 4
  for (int k = 0; k < H; ++k) {
    float4 w = W4[k * 32 + m4];
    float x0 = xs[ng * 4 + 0][k];
    float x1 = xs[ng * 4 + 1][k];
    float x2 = xs[ng * 4 + 2][k];
    float x3 = xs[ng * 4 + 3][k];
    a0.x += w.x * x0; a0.y += w.y * x0; a0.z += w.z * x0; a0.w += w.w * x0;
    a1.x += w.x * x1; a1.y += w.y * x1; a1.z += w.z * x1; a1.w += w.w * x1;
    a2.x += w.x * x2; a2.y += w.y * x2; a2.z += w.z * x2; a2.w += w.w * x2;
    a3.x += w.x * x3; a3.y += w.y * x3; a3.z += w.z * x3; a3.w += w.w * x3;
  }
  float4 av[4] = {a0, a1, a2, a3};
#pragma unroll
  for (int j = 0; j < 4; ++j) {
    int node = n0 + ng * 4 + j;
    if (node < n) {
      float d = dis[node];
      uint2 o;
      o.x = bf_pack(av[j].x * d, av[j].y * d);
      o.y = bf_pack(av[j].z * d, av[j].w * d);
      *(uint2*)&hs[node * 64 + m4 * 2] = o;
    }
  }
}

// ---------- gather: one node per wave, 2 bf16 feats per lane ----------
// out[d] = dis[d] * ( hs[d] + sum_{s in N_in(d)} hs[s] ) [+b][relu]
template <bool RELU, bool BIAS>
__global__ void k_gather(const int* __restrict__ offs, const int* __restrict__ csr,
                         const float* __restrict__ dis, const unsigned* __restrict__ hs,
                         const float* __restrict__ b, float2* __restrict__ out, int n) {
  int node = (blockIdx.x * blockDim.x + threadIdx.x) >> 6;
  int lane = threadIdx.x & 63;
  if (node >= n) return;
  unsigned self = hs[node * 64 + lane];
  float sx = bf_lo(self), sy = bf_hi(self);
  float tx = 0.f, ty = 0.f;
  int beg = offs[node], end = offs[node + 1];
  int e = beg;
  for (; e + 7 < end; e += 8) {
    int s0 = csr[e],     s1 = csr[e + 1], s2 = csr[e + 2], s3 = csr[e + 3];
    int s4 = csr[e + 4], s5 = csr[e + 5], s6 = csr[e + 6], s7 = csr[e + 7];
    unsigned v0 = hs[s0 * 64 + lane], v1 = hs[s1 * 64 + lane];
    unsigned v2 = hs[s2 * 64 + lane], v3 = hs[s3 * 64 + lane];
    unsigned v4 = hs[s4 * 64 + lane], v5 = hs[s5 * 64 + lane];
    unsigned v6 = hs[s6 * 64 + lane], v7 = hs[s7 * 64 + lane];
    sx += bf_lo(v0) + bf_lo(v1) + bf_lo(v2) + bf_lo(v3);
    sy += bf_hi(v0) + bf_hi(v1) + bf_hi(v2) + bf_hi(v3);
    tx += bf_lo(v4) + bf_lo(v5) + bf_lo(v6) + bf_lo(v7);
    ty += bf_hi(v4) + bf_hi(v5) + bf_hi(v6) + bf_hi(v7);
  }
  for (; e < end; ++e) {
    int s0 = csr[e];
    unsigned v0 = hs[s0 * 64 + lane];
    sx += bf_lo(v0); sy += bf_hi(v0);
  }
  float dd = dis[node];
  float vx = (sx + tx) * dd, vy = (sy + ty) * dd;
  if (BIAS) {
    const float2* b2 = (const float2*)b;
    float2 bb = b2[lane];
    vx += bb.x; vy += bb.y;
  }
  if (RELU) { vx = fmaxf(vx, 0.f); vy = fmaxf(vy, 0.f); }
  float2 o; o.x = vx; o.y = vy;
  out[node * 64 + lane] = o;
}

// ---------- pooling / output ----------

__global__ void k_zero_pool(float* pool, float* cnt) {
  int i = blockIdx.x * blockDim.x + threadIdx.x;
  if (i < NG * H) pool[i] = 0.f;
  if (i < NG) cnt[i] = 0.f;
}

__global__ void k_pool(const float* __restrict__ acc, const float* __restrict__ b3,
                       const int* __restrict__ batch, float* pool, float* cnt, int n) {
  int m = threadIdx.x;
  int n0 = blockIdx.x * 64;
  float run = 0.f, crun = 0.f;
  int curg = -1;
  float bm = b3[m];
  for (int i = 0; i < 64; ++i) {
    int node = n0 + i;
    if (node >= n) break;
    int g = batch[node];
    if (g != curg) {
      if (curg >= 0) {
        atomicAdd(&pool[curg * H + m], run);
        if (m == 0) atomicAdd(&cnt[curg], crun);
      }
      curg = g; run = 0.f; crun = 0.f;
    }
    run += acc[node * H + m] + bm;
    crun += 1.f;
  }
  if (curg >= 0) {
    atomicAdd(&pool[curg * H + m], run);
    if (m == 0) atomicAdd(&cnt[curg], crun);
  }
}

__global__ void k_out(const float* __restrict__ pool, const float* __restrict__ cnt,
                      const float* __restrict__ Wlin, const float* __restrict__ blin,
                      float* __restrict__ out) {
  int t = threadIdx.x;
  if (t >= NG * 3) return;
  int g = t / 3, c = t % 3;
  float invc = 1.f / fmaxf(cnt[g], 1.f);
  float s = 0.f;
  for (int m = 0; m < H; ++m) s += pool[g * H + m] * Wlin[m * 3 + c];
  out[t] = s * invc + blin[c];
}

extern "C" void kernel_launch(void* const* d_in, const int* in_sizes, int n_in,
                              void* d_out, int out_size, void* d_ws, size_t ws_size,
                              hipStream_t stream) {
  const float* x     = (const float*)d_in[0];
  const int*   ei    = (const int*)d_in[1];
  const int*   batch = (const int*)d_in[2];
  const float* W1    = (const float*)d_in[3];
  const float* b1    = (const float*)d_in[4];
  const float* W2    = (const float*)d_in[5];
  const float* b2    = (const float*)d_in[6];
  const float* W3    = (const float*)d_in[7];
  const float* b3    = (const float*)d_in[8];
  const float* Wlin  = (const float*)d_in[9];
  const float* blin  = (const float*)d_in[10];
  float* out = (float*)d_out;

  char* ws = (char*)d_ws;
  float*    dis   = (float*)ws;     ws += sizeof(float) * NN;
  unsigned* hs    = (unsigned*)ws;  ws += sizeof(ushort) * (size_t)NN * H;  // bf16
  float*    xbuf  = (float*)ws;     ws += sizeof(float) * (size_t)NN * H;
  float*    pool  = (float*)ws;     ws += sizeof(float) * NG * H;
  float*    cnt   = (float*)ws;     ws += sizeof(float) * NG;
  int*      indeg = (int*)ws;       ws += sizeof(int) * NN;
  int*      offs  = (int*)ws;       ws += sizeof(int) * (NN + 1);
  int*      rank  = (int*)ws;       ws += sizeof(int) * NE;
  int*      csr   = (int*)ws;       ws += sizeof(int) * NE;
  int*      bsum  = (int*)ws;       ws += sizeof(int) * NBLK;
  int*      boff  = (int*)ws;       ws += sizeof(int) * NBLK;

  // CSR build (parallel scan, rank-based fill — no fill atomics)
  k_zero_int<<<(NN + 255) / 256, 256, 0, stream>>>(indeg, NN);
  k_indeg_rank<<<2048, 256, 0, stream>>>(ei, indeg, rank, NE);
  k_blocksum<<<NBLK, 256, 0, stream>>>(indeg, bsum, NN);
  k_scanbsum<<<1, 64, 0, stream>>>(bsum, boff, offs, NBLK, NN);
  k_scanfinal<<<NBLK, 256, 0, stream>>>(indeg, boff, offs, dis, NN);
  k_fill<<<2048, 256, 0, stream>>>(ei, offs, rank, csr, NE);
  k_zero_pool<<<(NG * H + 255) / 256, 256, 0, stream>>>(pool, cnt);

  const int GATHER_GRID = (NN + 3) / 4;   // 1 node per wave, 4 waves/block

  // layer 1
  k_mm10<<<NN, 128, 0, stream>>>(x, W1, dis, (ushort*)hs, NN);
  k_gather<true, true><<<GATHER_GRID, 256, 0, stream>>>(
      offs, csr, dis, hs, b1, (float2*)xbuf, NN);

  // layer 2
  k_mm128<<<(NN + 31) / 32, 256, 0, stream>>>(xbuf, W2, dis, hs, NN);
  k_gather<true, true><<<GATHER_GRID, 256, 0, stream>>>(
      offs, csr, dis, hs, b2, (float2*)xbuf, NN);

  // layer 3
  k_mm128<<<(NN + 31) / 32, 256, 0, stream>>>(xbuf, W3, dis, hs, NN);
  k_gather<false, false><<<GATHER_GRID, 256, 0, stream>>>(
      offs, csr, dis, hs, nullptr, (float2*)xbuf, NN);

  // pool + head
  k_pool<<<(NN + 63) / 64, 128, 0, stream>>>(xbuf, b3, batch, pool, cnt, NN);
  k_out<<<1, 256, 0, stream>>>(pool, cnt, Wlin, blin, out);
}

// Round 6
// 465.817 us; speedup vs baseline: 4.9416x; 1.1187x over previous
//
#include <hip/hip_runtime.h>

constexpr int NN = 100000;
constexpr int NE = 1600000;
constexpr int NG = 64;
constexpr int H  = 128;
constexpr int SCAN_CHUNK = 1024;
constexpr int NBLK = (NN + SCAN_CHUNK - 1) / SCAN_CHUNK;  // 98
constexpr int NPART = 8;  // XCD-private histogram partitions

// ---------- bf16 helpers ----------
__device__ __forceinline__ float bf_lo(unsigned v) { return __uint_as_float(v << 16); }
__device__ __forceinline__ float bf_hi(unsigned v) { return __uint_as_float(v & 0xffff0000u); }
__device__ __forceinline__ unsigned bf_pack(float a, float b) {  // RTNE
  unsigned ua = __float_as_uint(a);
  unsigned ub = __float_as_uint(b);
  ua += 0x7fffu + ((ua >> 16) & 1u);
  ub += 0x7fffu + ((ub >> 16) & 1u);
  return (ua >> 16) | (ub & 0xffff0000u);
}

// ---------- CSR build ----------

__global__ void k_zero_int(int* p, int n) {
  int i = blockIdx.x * blockDim.x + threadIdx.x;
  if (i < n) p[i] = 0;
}

// XCD-private histograms: partition by blockIdx&7 (~XCD on default round-robin
// dispatch). rank packs (local_rank<<3)|part; correctness independent of mapping.
__global__ void k_indeg_rank(const int* __restrict__ ei, int* __restrict__ hist,
                             int* __restrict__ rank, int ne) {
  int part = blockIdx.x & (NPART - 1);
  int* h = hist + part * NN;
  int stride = gridDim.x * blockDim.x;
  for (int e = blockIdx.x * blockDim.x + threadIdx.x; e < ne; e += stride) {
    int lr = atomicAdd(&h[ei[ne + e]], 1);
    rank[e] = (lr << 3) | part;
  }
}

__global__ void k_blocksum(const int* __restrict__ hist, int* __restrict__ bsum, int n) {
  int t = threadIdx.x;
  int base = blockIdx.x * SCAN_CHUNK + t * 4;
  int s = 0;
  if (base + 3 < n) {
#pragma unroll
    for (int x = 0; x < NPART; ++x) {
      int4 v = *(const int4*)&hist[x * NN + base];
      s += v.x + v.y + v.z + v.w;
    }
  } else {
#pragma unroll
    for (int x = 0; x < NPART; ++x)
      for (int i = 0; i < 4; ++i)
        if (base + i < n) s += hist[x * NN + base + i];
  }
#pragma unroll
  for (int off = 32; off; off >>= 1) s += __shfl_down(s, off, 64);
  __shared__ int ws[4];
  if ((t & 63) == 0) ws[t >> 6] = s;
  __syncthreads();
  if (t == 0) bsum[blockIdx.x] = ws[0] + ws[1] + ws[2] + ws[3];
}

__global__ void k_scanbsum(const int* __restrict__ bsum, int* __restrict__ boff,
                           int* __restrict__ offs, int nb, int n) {
  if (threadIdx.x == 0) {
    int run = 0;
    for (int i = 0; i < nb; ++i) { int v = bsum[i]; boff[i] = run; run += v; }
    offs[n] = run;
  }
}

// per-node totals + per-partition base cursors
__global__ void k_scanfinal(const int* __restrict__ hist, const int* __restrict__ boff,
                            int* __restrict__ offs, int* __restrict__ base_out,
                            float* __restrict__ dis, int n) {
  int t = threadIdx.x;
  int base = blockIdx.x * SCAN_CHUNK + t * 4;
  int hv[NPART][4];
  int v[4];
  if (base + 3 < n) {
#pragma unroll
    for (int x = 0; x < NPART; ++x) {
      int4 q = *(const int4*)&hist[x * NN + base];
      hv[x][0] = q.x; hv[x][1] = q.y; hv[x][2] = q.z; hv[x][3] = q.w;
    }
  } else {
#pragma unroll
    for (int x = 0; x < NPART; ++x)
      for (int i = 0; i < 4; ++i)
        hv[x][i] = (base + i < n) ? hist[x * NN + base + i] : 0;
  }
#pragma unroll
  for (int i = 0; i < 4; ++i) {
    int s = 0;
#pragma unroll
    for (int x = 0; x < NPART; ++x) s += hv[x][i];
    v[i] = s;
  }
  int s = v[0] + v[1] + v[2] + v[3];

  int lane = t & 63, w = t >> 6;
  int inc = s;
#pragma unroll
  for (int off = 1; off < 64; off <<= 1) {
    int y = __shfl_up(inc, off, 64);
    if (lane >= off) inc += y;
  }
  __shared__ int wsum[4];
  if (lane == 63) wsum[w] = inc;
  __syncthreads();
  int woff = 0;
  for (int i = 0; i < w; ++i) woff += wsum[i];
  int run = woff + (inc - s) + boff[blockIdx.x];

  // per-node start offsets + dis
  int starts[4];
  {
    int r = run;
#pragma unroll
    for (int i = 0; i < 4; ++i) { starts[i] = r; r += v[i]; }
  }
  if (base + 3 < n) {
    *(int4*)&offs[base] = make_int4(starts[0], starts[1], starts[2], starts[3]);
    float4 dv;
    dv.x = rsqrtf((float)(v[0] + 1));
    dv.y = rsqrtf((float)(v[1] + 1));
    dv.z = rsqrtf((float)(v[2] + 1));
    dv.w = rsqrtf((float)(v[3] + 1));
    *(float4*)&dis[base] = dv;
#pragma unroll
    for (int x = 0; x < NPART; ++x) {
      int4 bv = make_int4(starts[0], starts[1], starts[2], starts[3]);
      *(int4*)&base_out[x * NN + base] = bv;
      starts[0] += hv[x][0]; starts[1] += hv[x][1];
      starts[2] += hv[x][2]; starts[3] += hv[x][3];
    }
  } else {
#pragma unroll
    for (int i = 0; i < 4; ++i) {
      if (base + i < n) {
        offs[base + i] = starts[i];
        dis[base + i] = rsqrtf((float)(v[i] + 1));
        int acc = starts[i];
#pragma unroll
        for (int x = 0; x < NPART; ++x) {
          base_out[x * NN + base + i] = acc;
          acc += hv[x][i];
        }
      }
    }
  }
}

__global__ void k_fill(const int* __restrict__ ei, const int* __restrict__ base_out,
                       const int* __restrict__ rank, int* __restrict__ csr, int ne) {
  int stride = gridDim.x * blockDim.x;
  for (int e = blockIdx.x * blockDim.x + threadIdx.x; e < ne; e += stride) {
    int s = ei[e];
    int d = ei[ne + e];
    int r = rank[e];
    int p = r & (NPART - 1);
    csr[base_out[p * NN + d] + (r >> 3)] = s;
  }
}

// ---------- layer 1: aggregate-first (A·X)·W1 ----------

// xs16[node][16] bf16 = x[node][0..9]*dis[node], padded with zeros
__global__ void k_prescale(const float* __restrict__ x, const float* __restrict__ dis,
                           unsigned* __restrict__ xs16, int n) {
  int i = blockIdx.x * blockDim.x + threadIdx.x;
  if (i >= n * 8) return;
  int node = i >> 3, j = i & 7;
  int f0 = 2 * j, f1 = 2 * j + 1;
  float d = dis[node];
  float a = (f0 < 10) ? x[node * 10 + f0] * d : 0.f;
  float b = (f1 < 10) ? x[node * 10 + f1] * d : 0.f;
  xs16[i] = bf_pack(a, b);
}

// agg[node][16] fp32 = dis_d * (xs16_d + sum_src xs16_s); 8 nodes/wave, 8 lanes/node
__global__ void k_gather16(const int* __restrict__ offs, const int* __restrict__ csr,
                           const float* __restrict__ dis, const unsigned* __restrict__ xs16,
                           float2* __restrict__ agg, int n) {
  int wid = (blockIdx.x * blockDim.x + threadIdx.x) >> 6;
  int lane = threadIdx.x & 63;
  int g = lane >> 3, sl = lane & 7;
  int node = wid * 8 + g;
  if (node >= n) return;
  unsigned self = xs16[node * 8 + sl];
  float sx = bf_lo(self), sy = bf_hi(self);
  int e = offs[node], end = offs[node + 1];
  for (; e + 1 < end; e += 2) {
    int s0 = csr[e], s1 = csr[e + 1];
    unsigned v0 = xs16[s0 * 8 + sl], v1 = xs16[s1 * 8 + sl];
    sx += bf_lo(v0) + bf_lo(v1);
    sy += bf_hi(v0) + bf_hi(v1);
  }
  if (e < end) {
    unsigned v0 = xs16[csr[e] * 8 + sl];
    sx += bf_lo(v0); sy += bf_hi(v0);
  }
  float dd = dis[node];
  float2 o; o.x = sx * dd; o.y = sy * dd;
  agg[node * 8 + sl] = o;
}

// xbuf[node][128] = relu(agg[node][0..9] @ W1 + b1)
__global__ void k_mm16(const float* __restrict__ agg, const float* __restrict__ W1,
                       const float* __restrict__ b1, float* __restrict__ xbuf, int n) {
  int node = blockIdx.x;
  if (node >= n) return;
  __shared__ float as[16];
  int m = threadIdx.x;
  if (m < 16) as[m] = agg[node * 16 + m];
  __syncthreads();
  float s = 0.f;
#pragma unroll
  for (int k = 0; k < 10; ++k) s += as[k] * W1[k * H + m];
  s += b1[m];
  xbuf[node * H + m] = fmaxf(s, 0.f);
}

// ---------- layers 2/3 dense: xin@W -> hs bf16 (pre-scaled by dis) ----------

__global__ void k_mm128(const float* __restrict__ xin, const float* __restrict__ W,
                        const float* __restrict__ dis, unsigned* __restrict__ hs, int n) {
  __shared__ float xs[32][H];
  int t = threadIdx.x;
  int n0 = blockIdx.x * 32;
#pragma unroll
  for (int i = 0; i < 4; ++i) {
    int f4 = i * 256 + t;
    int row = f4 >> 5, c4 = f4 & 31;
    float4 v = *(const float4*)&xin[(n0 + row) * H + c4 * 4];
    *(float4*)&xs[row][c4 * 4] = v;
  }
  __syncthreads();
  int m4 = t & 31, ng = t >> 5;
  float4 a0 = {0,0,0,0}, a1 = {0,0,0,0}, a2 = {0,0,0,0}, a3 = {0,0,0,0};
  const float4* W4 = (const float4*)W;
#pragma unroll 4
  for (int k = 0; k < H; ++k) {
    float4 w = W4[k * 32 + m4];
    float x0 = xs[ng * 4 + 0][k];
    float x1 = xs[ng * 4 + 1][k];
    float x2 = xs[ng * 4 + 2][k];
    float x3 = xs[ng * 4 + 3][k];
    a0.x += w.x * x0; a0.y += w.y * x0; a0.z += w.z * x0; a0.w += w.w * x0;
    a1.x += w.x * x1; a1.y += w.y * x1; a1.z += w.z * x1; a1.w += w.w * x1;
    a2.x += w.x * x2; a2.y += w.y * x2; a2.z += w.z * x2; a2.w += w.w * x2;
    a3.x += w.x * x3; a3.y += w.y * x3; a3.z += w.z * x3; a3.w += w.w * x3;
  }
  float4 av[4] = {a0, a1, a2, a3};
#pragma unroll
  for (int j = 0; j < 4; ++j) {
    int node = n0 + ng * 4 + j;
    if (node < n) {
      float d = dis[node];
      uint2 o;
      o.x = bf_pack(av[j].x * d, av[j].y * d);
      o.y = bf_pack(av[j].z * d, av[j].w * d);
      *(uint2*)&hs[node * 64 + m4 * 2] = o;
    }
  }
}

// ---------- gather 128-wide: one node per wave, 2 bf16 feats per lane ----------
template <bool RELU, bool BIAS>
__global__ void k_gather(const int* __restrict__ offs, const int* __restrict__ csr,
                         const float* __restrict__ dis, const unsigned* __restrict__ hs,
                         const float* __restrict__ b, float2* __restrict__ out, int n) {
  int node = (blockIdx.x * blockDim.x + threadIdx.x) >> 6;
  int lane = threadIdx.x & 63;
  if (node >= n) return;
  unsigned self = hs[node * 64 + lane];
  float sx = bf_lo(self), sy = bf_hi(self);
  float tx = 0.f, ty = 0.f;
  int beg = offs[node], end = offs[node + 1];
  int e = beg;
  for (; e + 7 < end; e += 8) {
    int s0 = csr[e],     s1 = csr[e + 1], s2 = csr[e + 2], s3 = csr[e + 3];
    int s4 = csr[e + 4], s5 = csr[e + 5], s6 = csr[e + 6], s7 = csr[e + 7];
    unsigned v0 = hs[s0 * 64 + lane], v1 = hs[s1 * 64 + lane];
    unsigned v2 = hs[s2 * 64 + lane], v3 = hs[s3 * 64 + lane];
    unsigned v4 = hs[s4 * 64 + lane], v5 = hs[s5 * 64 + lane];
    unsigned v6 = hs[s6 * 64 + lane], v7 = hs[s7 * 64 + lane];
    sx += bf_lo(v0) + bf_lo(v1) + bf_lo(v2) + bf_lo(v3);
    sy += bf_hi(v0) + bf_hi(v1) + bf_hi(v2) + bf_hi(v3);
    tx += bf_lo(v4) + bf_lo(v5) + bf_lo(v6) + bf_lo(v7);
    ty += bf_hi(v4) + bf_hi(v5) + bf_hi(v6) + bf_hi(v7);
  }
  for (; e < end; ++e) {
    unsigned v0 = hs[csr[e] * 64 + lane];
    sx += bf_lo(v0); sy += bf_hi(v0);
  }
  float dd = dis[node];
  float vx = (sx + tx) * dd, vy = (sy + ty) * dd;
  if (BIAS) {
    const float2* b2 = (const float2*)b;
    float2 bb = b2[lane];
    vx += bb.x; vy += bb.y;
  }
  if (RELU) { vx = fmaxf(vx, 0.f); vy = fmaxf(vy, 0.f); }
  float2 o; o.x = vx; o.y = vy;
  out[node * 64 + lane] = o;
}

// ---------- pooling / output ----------

__global__ void k_zero_pool(float* pool, float* cnt) {
  int i = blockIdx.x * blockDim.x + threadIdx.x;
  if (i < NG * H) pool[i] = 0.f;
  if (i < NG) cnt[i] = 0.f;
}

__global__ void k_pool(const float* __restrict__ acc, const float* __restrict__ b3,
                       const int* __restrict__ batch, float* pool, float* cnt, int n) {
  int m = threadIdx.x;
  int n0 = blockIdx.x * 64;
  float run = 0.f, crun = 0.f;
  int curg = -1;
  float bm = b3[m];
  for (int i = 0; i < 64; ++i) {
    int node = n0 + i;
    if (node >= n) break;
    int g = batch[node];
    if (g != curg) {
      if (curg >= 0) {
        atomicAdd(&pool[curg * H + m], run);
        if (m == 0) atomicAdd(&cnt[curg], crun);
      }
      curg = g; run = 0.f; crun = 0.f;
    }
    run += acc[node * H + m] + bm;
    crun += 1.f;
  }
  if (curg >= 0) {
    atomicAdd(&pool[curg * H + m], run);
    if (m == 0) atomicAdd(&cnt[curg], crun);
  }
}

__global__ void k_out(const float* __restrict__ pool, const float* __restrict__ cnt,
                      const float* __restrict__ Wlin, const float* __restrict__ blin,
                      float* __restrict__ out) {
  int t = threadIdx.x;
  if (t >= NG * 3) return;
  int g = t / 3, c = t % 3;
  float invc = 1.f / fmaxf(cnt[g], 1.f);
  float s = 0.f;
  for (int m = 0; m < H; ++m) s += pool[g * H + m] * Wlin[m * 3 + c];
  out[t] = s * invc + blin[c];
}

extern "C" void kernel_launch(void* const* d_in, const int* in_sizes, int n_in,
                              void* d_out, int out_size, void* d_ws, size_t ws_size,
                              hipStream_t stream) {
  const float* x     = (const float*)d_in[0];
  const int*   ei    = (const int*)d_in[1];
  const int*   batch = (const int*)d_in[2];
  const float* W1    = (const float*)d_in[3];
  const float* b1    = (const float*)d_in[4];
  const float* W2    = (const float*)d_in[5];
  const float* b2    = (const float*)d_in[6];
  const float* W3    = (const float*)d_in[7];
  const float* b3    = (const float*)d_in[8];
  const float* Wlin  = (const float*)d_in[9];
  const float* blin  = (const float*)d_in[10];
  float* out = (float*)d_out;

  char* ws = (char*)d_ws;
  float*    dis   = (float*)ws;     ws += sizeof(float) * NN;
  unsigned* hs    = (unsigned*)ws;  ws += sizeof(ushort) * (size_t)NN * H;  // bf16
  float*    xbuf  = (float*)ws;     ws += sizeof(float) * (size_t)NN * H;
  unsigned* xs16  = (unsigned*)ws;  ws += sizeof(unsigned) * (size_t)NN * 8;
  float*    agg   = (float*)ws;     ws += sizeof(float) * (size_t)NN * 16;
  float*    pool  = (float*)ws;     ws += sizeof(float) * NG * H;
  float*    cnt   = (float*)ws;     ws += sizeof(float) * NG;
  int*      hist  = (int*)ws;       ws += sizeof(int) * NPART * NN;
  int*      baseo = (int*)ws;       ws += sizeof(int) * NPART * NN;
  int*      offs  = (int*)ws;       ws += sizeof(int) * (NN + 8);
  int*      rank  = (int*)ws;       ws += sizeof(int) * NE;
  int*      csr   = (int*)ws;       ws += sizeof(int) * NE;
  int*      bsum  = (int*)ws;       ws += sizeof(int) * NBLK;
  int*      boff  = (int*)ws;       ws += sizeof(int) * NBLK;

  // CSR build: XCD-partitioned histogram + rank, scan, atomic-free fill
  k_zero_int<<<(NPART * NN + 255) / 256, 256, 0, stream>>>(hist, NPART * NN);
  k_indeg_rank<<<2048, 256, 0, stream>>>(ei, hist, rank, NE);
  k_blocksum<<<NBLK, 256, 0, stream>>>(hist, bsum, NN);
  k_scanbsum<<<1, 64, 0, stream>>>(bsum, boff, offs, NBLK, NN);
  k_scanfinal<<<NBLK, 256, 0, stream>>>(hist, boff, offs, baseo, dis, NN);
  k_fill<<<2048, 256, 0, stream>>>(ei, baseo, rank, csr, NE);
  k_zero_pool<<<(NG * H + 255) / 256, 256, 0, stream>>>(pool, cnt);

  const int GATHER_GRID = (NN + 3) / 4;   // 1 node/wave, 4 waves/block

  // layer 1: aggregate-first (A·X)·W1
  k_prescale<<<(NN * 8 + 255) / 256, 256, 0, stream>>>(x, dis, xs16, NN);
  k_gather16<<<(NN + 31) / 32, 256, 0, stream>>>(offs, csr, dis, xs16, (float2*)agg, NN);
  k_mm16<<<NN, 128, 0, stream>>>(agg, W1, b1, xbuf, NN);

  // layer 2
  k_mm128<<<(NN + 31) / 32, 256, 0, stream>>>(xbuf, W2, dis, hs, NN);
  k_gather<true, true><<<GATHER_GRID, 256, 0, stream>>>(
      offs, csr, dis, hs, b2, (float2*)xbuf, NN);

  // layer 3
  k_mm128<<<(NN + 31) / 32, 256, 0, stream>>>(xbuf, W3, dis, hs, NN);
  k_gather<false, false><<<GATHER_GRID, 256, 0, stream>>>(
      offs, csr, dis, hs, nullptr, (float2*)xbuf, NN);

  // pool + head
  k_pool<<<(NN + 63) / 64, 128, 0, stream>>>(xbuf, b3, batch, pool, cnt, NN);
  k_out<<<1, 256, 0, stream>>>(pool, cnt, Wlin, blin, out);
}

// Round 7
// 452.064 us; speedup vs baseline: 5.0920x; 1.0304x over previous
//
#include <hip/hip_runtime.h>

constexpr int NN = 100000;
constexpr int NE = 1600000;
constexpr int NG = 64;
constexpr int H  = 128;
constexpr int SCAN_CHUNK = 1024;
constexpr int NBLK = (NN + SCAN_CHUNK - 1) / SCAN_CHUNK;  // 98
constexpr int NPART = 8;  // XCD-private histogram partitions

typedef float v2f __attribute__((ext_vector_type(2)));

// ---------- bf16 helpers ----------
__device__ __forceinline__ float bf_lo(unsigned v) { return __uint_as_float(v << 16); }
__device__ __forceinline__ float bf_hi(unsigned v) { return __uint_as_float(v & 0xffff0000u); }
__device__ __forceinline__ unsigned bf_pack(float a, float b) {  // RTNE
  unsigned ua = __float_as_uint(a);
  unsigned ub = __float_as_uint(b);
  ua += 0x7fffu + ((ua >> 16) & 1u);
  ub += 0x7fffu + ((ub >> 16) & 1u);
  return (ua >> 16) | (ub & 0xffff0000u);
}

// ---------- CSR build ----------

__global__ void k_zero_int(int* p, int n) {
  int i = blockIdx.x * blockDim.x + threadIdx.x;
  if (i < n) p[i] = 0;
}

// XCD-private histograms: partition by blockIdx&7 (~XCD on default round-robin
// dispatch). rank packs (local_rank<<3)|part; correctness independent of mapping.
__global__ void k_indeg_rank(const int* __restrict__ ei, int* __restrict__ hist,
                             int* __restrict__ rank, int ne) {
  int part = blockIdx.x & (NPART - 1);
  int* h = hist + part * NN;
  int stride = gridDim.x * blockDim.x;
  for (int e = blockIdx.x * blockDim.x + threadIdx.x; e < ne; e += stride) {
    int lr = atomicAdd(&h[ei[ne + e]], 1);
    rank[e] = (lr << 3) | part;
  }
}

__global__ void k_blocksum(const int* __restrict__ hist, int* __restrict__ bsum, int n) {
  int t = threadIdx.x;
  int base = blockIdx.x * SCAN_CHUNK + t * 4;
  int s = 0;
  if (base + 3 < n) {
#pragma unroll
    for (int x = 0; x < NPART; ++x) {
      int4 v = *(const int4*)&hist[x * NN + base];
      s += v.x + v.y + v.z + v.w;
    }
  } else {
#pragma unroll
    for (int x = 0; x < NPART; ++x)
      for (int i = 0; i < 4; ++i)
        if (base + i < n) s += hist[x * NN + base + i];
  }
#pragma unroll
  for (int off = 32; off; off >>= 1) s += __shfl_down(s, off, 64);
  __shared__ int ws[4];
  if ((t & 63) == 0) ws[t >> 6] = s;
  __syncthreads();
  if (t == 0) bsum[blockIdx.x] = ws[0] + ws[1] + ws[2] + ws[3];
}

__global__ void k_scanbsum(const int* __restrict__ bsum, int* __restrict__ boff,
                           int* __restrict__ offs, int nb, int n) {
  if (threadIdx.x == 0) {
    int run = 0;
    for (int i = 0; i < nb; ++i) { int v = bsum[i]; boff[i] = run; run += v; }
    offs[n] = run;
  }
}

// per-node totals + per-partition base cursors
__global__ void k_scanfinal(const int* __restrict__ hist, const int* __restrict__ boff,
                            int* __restrict__ offs, int* __restrict__ base_out,
                            float* __restrict__ dis, int n) {
  int t = threadIdx.x;
  int base = blockIdx.x * SCAN_CHUNK + t * 4;
  int hv[NPART][4];
  int v[4];
  if (base + 3 < n) {
#pragma unroll
    for (int x = 0; x < NPART; ++x) {
      int4 q = *(const int4*)&hist[x * NN + base];
      hv[x][0] = q.x; hv[x][1] = q.y; hv[x][2] = q.z; hv[x][3] = q.w;
    }
  } else {
#pragma unroll
    for (int x = 0; x < NPART; ++x)
      for (int i = 0; i < 4; ++i)
        hv[x][i] = (base + i < n) ? hist[x * NN + base + i] : 0;
  }
#pragma unroll
  for (int i = 0; i < 4; ++i) {
    int s = 0;
#pragma unroll
    for (int x = 0; x < NPART; ++x) s += hv[x][i];
    v[i] = s;
  }
  int s = v[0] + v[1] + v[2] + v[3];

  int lane = t & 63, w = t >> 6;
  int inc = s;
#pragma unroll
  for (int off = 1; off < 64; off <<= 1) {
    int y = __shfl_up(inc, off, 64);
    if (lane >= off) inc += y;
  }
  __shared__ int wsum[4];
  if (lane == 63) wsum[w] = inc;
  __syncthreads();
  int woff = 0;
  for (int i = 0; i < w; ++i) woff += wsum[i];
  int run = woff + (inc - s) + boff[blockIdx.x];

  int starts[4];
  {
    int r = run;
#pragma unroll
    for (int i = 0; i < 4; ++i) { starts[i] = r; r += v[i]; }
  }
  if (base + 3 < n) {
    *(int4*)&offs[base] = make_int4(starts[0], starts[1], starts[2], starts[3]);
    float4 dv;
    dv.x = rsqrtf((float)(v[0] + 1));
    dv.y = rsqrtf((float)(v[1] + 1));
    dv.z = rsqrtf((float)(v[2] + 1));
    dv.w = rsqrtf((float)(v[3] + 1));
    *(float4*)&dis[base] = dv;
#pragma unroll
    for (int x = 0; x < NPART; ++x) {
      int4 bv = make_int4(starts[0], starts[1], starts[2], starts[3]);
      *(int4*)&base_out[x * NN + base] = bv;
      starts[0] += hv[x][0]; starts[1] += hv[x][1];
      starts[2] += hv[x][2]; starts[3] += hv[x][3];
    }
  } else {
#pragma unroll
    for (int i = 0; i < 4; ++i) {
      if (base + i < n) {
        offs[base + i] = starts[i];
        dis[base + i] = rsqrtf((float)(v[i] + 1));
        int acc = starts[i];
#pragma unroll
        for (int x = 0; x < NPART; ++x) {
          base_out[x * NN + base + i] = acc;
          acc += hv[x][i];
        }
      }
    }
  }
}

__global__ void k_fill(const int* __restrict__ ei, const int* __restrict__ base_out,
                       const int* __restrict__ rank, int* __restrict__ csr, int ne) {
  int stride = gridDim.x * blockDim.x;
  for (int e = blockIdx.x * blockDim.x + threadIdx.x; e < ne; e += stride) {
    int s = ei[e];
    int d = ei[ne + e];
    int r = rank[e];
    int p = r & (NPART - 1);
    csr[base_out[p * NN + d] + (r >> 3)] = s;
  }
}

// ---------- layer 1: aggregate-first (A·X)·W1 ----------

__global__ void k_prescale(const float* __restrict__ x, const float* __restrict__ dis,
                           unsigned* __restrict__ xs16, int n) {
  int i = blockIdx.x * blockDim.x + threadIdx.x;
  if (i >= n * 8) return;
  int node = i >> 3, j = i & 7;
  int f0 = 2 * j, f1 = 2 * j + 1;
  float d = dis[node];
  float a = (f0 < 10) ? x[node * 10 + f0] * d : 0.f;
  float b = (f1 < 10) ? x[node * 10 + f1] * d : 0.f;
  xs16[i] = bf_pack(a, b);
}

__global__ void k_gather16(const int* __restrict__ offs, const int* __restrict__ csr,
                           const float* __restrict__ dis, const unsigned* __restrict__ xs16,
                           float2* __restrict__ agg, int n) {
  int wid = (blockIdx.x * blockDim.x + threadIdx.x) >> 6;
  int lane = threadIdx.x & 63;
  int g = lane >> 3, sl = lane & 7;
  int node = wid * 8 + g;
  if (node >= n) return;
  unsigned self = xs16[node * 8 + sl];
  float sx = bf_lo(self), sy = bf_hi(self);
  int e = offs[node], end = offs[node + 1];
  for (; e + 1 < end; e += 2) {
    int s0 = csr[e], s1 = csr[e + 1];
    unsigned v0 = xs16[s0 * 8 + sl], v1 = xs16[s1 * 8 + sl];
    sx += bf_lo(v0) + bf_lo(v1);
    sy += bf_hi(v0) + bf_hi(v1);
  }
  if (e < end) {
    unsigned v0 = xs16[csr[e] * 8 + sl];
    sx += bf_lo(v0); sy += bf_hi(v0);
  }
  float dd = dis[node];
  float2 o; o.x = sx * dd; o.y = sy * dd;
  agg[node * 8 + sl] = o;
}

__global__ void k_mm16(const float* __restrict__ agg, const float* __restrict__ W1,
                       const float* __restrict__ b1, float* __restrict__ xbuf, int n) {
  int node = blockIdx.x;
  if (node >= n) return;
  __shared__ float as[16];
  int m = threadIdx.x;
  if (m < 16) as[m] = agg[node * 16 + m];
  __syncthreads();
  float s = 0.f;
#pragma unroll
  for (int k = 0; k < 10; ++k) s += as[k] * W1[k * H + m];
  s += b1[m];
  xbuf[node * H + m] = fmaxf(s, 0.f);
}

// ---------- layers 2/3 dense: xin@W -> hs fp8 e4m3 (pre-scaled by dis) ----------

__global__ void k_mm128(const float* __restrict__ xin, const float* __restrict__ W,
                        const float* __restrict__ dis, unsigned* __restrict__ hs8, int n) {
  __shared__ float xs[32][H];
  int t = threadIdx.x;
  int n0 = blockIdx.x * 32;
#pragma unroll
  for (int i = 0; i < 4; ++i) {
    int f4 = i * 256 + t;
    int row = f4 >> 5, c4 = f4 & 31;
    float4 v = *(const float4*)&xin[(n0 + row) * H + c4 * 4];
    *(float4*)&xs[row][c4 * 4] = v;
  }
  __syncthreads();
  int m4 = t & 31, ng = t >> 5;
  float4 a0 = {0,0,0,0}, a1 = {0,0,0,0}, a2 = {0,0,0,0}, a3 = {0,0,0,0};
  const float4* W4 = (const float4*)W;
#pragma unroll 4
  for (int k = 0; k < H; ++k) {
    float4 w = W4[k * 32 + m4];
    float x0 = xs[ng * 4 + 0][k];
    float x1 = xs[ng * 4 + 1][k];
    float x2 = xs[ng * 4 + 2][k];
    float x3 = xs[ng * 4 + 3][k];
    a0.x += w.x * x0; a0.y += w.y * x0; a0.z += w.z * x0; a0.w += w.w * x0;
    a1.x += w.x * x1; a1.y += w.y * x1; a1.z += w.z * x1; a1.w += w.w * x1;
    a2.x += w.x * x2; a2.y += w.y * x2; a2.z += w.z * x2; a2.w += w.w * x2;
    a3.x += w.x * x3; a3.y += w.y * x3; a3.z += w.z * x3; a3.w += w.w * x3;
  }
  float4 av[4] = {a0, a1, a2, a3};
#pragma unroll
  for (int j = 0; j < 4; ++j) {
    int node = n0 + ng * 4 + j;
    if (node < n) {
      float d = dis[node];
      int pk = __builtin_amdgcn_cvt_pk_fp8_f32(av[j].x * d, av[j].y * d, 0, false);
      pk = __builtin_amdgcn_cvt_pk_fp8_f32(av[j].z * d, av[j].w * d, pk, true);
      hs8[node * 32 + m4] = (unsigned)pk;   // 4 fp8 feats per u32
    }
  }
}

// ---------- gather 128-wide: one node per wave, 2 fp8 feats per lane ----------
template <bool RELU, bool BIAS>
__global__ void k_gather(const int* __restrict__ offs, const int* __restrict__ csr,
                         const float* __restrict__ dis, const ushort* __restrict__ hs8,
                         const float* __restrict__ b, float2* __restrict__ out, int n) {
  int node = (blockIdx.x * blockDim.x + threadIdx.x) >> 6;
  int lane = threadIdx.x & 63;
  if (node >= n) return;
  v2f self = __builtin_amdgcn_cvt_pk_f32_fp8((int)hs8[node * 64 + lane], false);
  float sx = self.x, sy = self.y;
  float tx = 0.f, ty = 0.f;
  int beg = offs[node], end = offs[node + 1];
  int e = beg;
  for (; e + 7 < end; e += 8) {
    int s0 = csr[e],     s1 = csr[e + 1], s2 = csr[e + 2], s3 = csr[e + 3];
    int s4 = csr[e + 4], s5 = csr[e + 5], s6 = csr[e + 6], s7 = csr[e + 7];
    int u0 = hs8[s0 * 64 + lane], u1 = hs8[s1 * 64 + lane];
    int u2 = hs8[s2 * 64 + lane], u3 = hs8[s3 * 64 + lane];
    int u4 = hs8[s4 * 64 + lane], u5 = hs8[s5 * 64 + lane];
    int u6 = hs8[s6 * 64 + lane], u7 = hs8[s7 * 64 + lane];
    v2f v0 = __builtin_amdgcn_cvt_pk_f32_fp8(u0, false);
    v2f v1 = __builtin_amdgcn_cvt_pk_f32_fp8(u1, false);
    v2f v2 = __builtin_amdgcn_cvt_pk_f32_fp8(u2, false);
    v2f v3 = __builtin_amdgcn_cvt_pk_f32_fp8(u3, false);
    v2f v4 = __builtin_amdgcn_cvt_pk_f32_fp8(u4, false);
    v2f v5 = __builtin_amdgcn_cvt_pk_f32_fp8(u5, false);
    v2f v6 = __builtin_amdgcn_cvt_pk_f32_fp8(u6, false);
    v2f v7 = __builtin_amdgcn_cvt_pk_f32_fp8(u7, false);
    sx += v0.x + v1.x + v2.x + v3.x;
    sy += v0.y + v1.y + v2.y + v3.y;
    tx += v4.x + v5.x + v6.x + v7.x;
    ty += v4.y + v5.y + v6.y + v7.y;
  }
  for (; e < end; ++e) {
    v2f v0 = __builtin_amdgcn_cvt_pk_f32_fp8((int)hs8[csr[e] * 64 + lane], false);
    sx += v0.x; sy += v0.y;
  }
  float dd = dis[node];
  float vx = (sx + tx) * dd, vy = (sy + ty) * dd;
  if (BIAS) {
    const float2* b2 = (const float2*)b;
    float2 bb = b2[lane];
    vx += bb.x; vy += bb.y;
  }
  if (RELU) { vx = fmaxf(vx, 0.f); vy = fmaxf(vy, 0.f); }
  float2 o; o.x = vx; o.y = vy;
  out[node * 64 + lane] = o;
}

// ---------- pooling / output ----------

__global__ void k_zero_pool(float* pool, float* cnt) {
  int i = blockIdx.x * blockDim.x + threadIdx.x;
  if (i < NG * H) pool[i] = 0.f;
  if (i < NG) cnt[i] = 0.f;
}

__global__ void k_pool(const float* __restrict__ acc, const float* __restrict__ b3,
                       const int* __restrict__ batch, float* pool, float* cnt, int n) {
  int m = threadIdx.x;
  int n0 = blockIdx.x * 64;
  float run = 0.f, crun = 0.f;
  int curg = -1;
  float bm = b3[m];
  for (int i = 0; i < 64; ++i) {
    int node = n0 + i;
    if (node >= n) break;
    int g = batch[node];
    if (g != curg) {
      if (curg >= 0) {
        atomicAdd(&pool[curg * H + m], run);
        if (m == 0) atomicAdd(&cnt[curg], crun);
      }
      curg = g; run = 0.f; crun = 0.f;
    }
    run += acc[node * H + m] + bm;
    crun += 1.f;
  }
  if (curg >= 0) {
    atomicAdd(&pool[curg * H + m], run);
    if (m == 0) atomicAdd(&cnt[curg], crun);
  }
}

__global__ void k_out(const float* __restrict__ pool, const float* __restrict__ cnt,
                      const float* __restrict__ Wlin, const float* __restrict__ blin,
                      float* __restrict__ out) {
  int t = threadIdx.x;
  if (t >= NG * 3) return;
  int g = t / 3, c = t % 3;
  float invc = 1.f / fmaxf(cnt[g], 1.f);
  float s = 0.f;
  for (int m = 0; m < H; ++m) s += pool[g * H + m] * Wlin[m * 3 + c];
  out[t] = s * invc + blin[c];
}

extern "C" void kernel_launch(void* const* d_in, const int* in_sizes, int n_in,
                              void* d_out, int out_size, void* d_ws, size_t ws_size,
                              hipStream_t stream) {
  const float* x     = (const float*)d_in[0];
  const int*   ei    = (const int*)d_in[1];
  const int*   batch = (const int*)d_in[2];
  const float* W1    = (const float*)d_in[3];
  const float* b1    = (const float*)d_in[4];
  const float* W2    = (const float*)d_in[5];
  const float* b2    = (const float*)d_in[6];
  const float* W3    = (const float*)d_in[7];
  const float* b3    = (const float*)d_in[8];
  const float* Wlin  = (const float*)d_in[9];
  const float* blin  = (const float*)d_in[10];
  float* out = (float*)d_out;

  char* ws = (char*)d_ws;
  float*    dis   = (float*)ws;     ws += sizeof(float) * NN;
  unsigned* hs8   = (unsigned*)ws;  ws += (size_t)NN * H;   // fp8, 1B/feat
  float*    xbuf  = (float*)ws;     ws += sizeof(float) * (size_t)NN * H;
  unsigned* xs16  = (unsigned*)ws;  ws += sizeof(unsigned) * (size_t)NN * 8;
  float*    agg   = (float*)ws;     ws += sizeof(float) * (size_t)NN * 16;
  float*    pool  = (float*)ws;     ws += sizeof(float) * NG * H;
  float*    cnt   = (float*)ws;     ws += sizeof(float) * NG;
  int*      hist  = (int*)ws;       ws += sizeof(int) * NPART * NN;
  int*      baseo = (int*)ws;       ws += sizeof(int) * NPART * NN;
  int*      offs  = (int*)ws;       ws += sizeof(int) * (NN + 8);
  int*      rank  = (int*)ws;       ws += sizeof(int) * NE;
  int*      csr   = (int*)ws;       ws += sizeof(int) * NE;
  int*      bsum  = (int*)ws;       ws += sizeof(int) * NBLK;
  int*      boff  = (int*)ws;       ws += sizeof(int) * NBLK;

  // CSR build: XCD-partitioned histogram + rank, scan, atomic-free fill
  k_zero_int<<<(NPART * NN + 255) / 256, 256, 0, stream>>>(hist, NPART * NN);
  k_indeg_rank<<<2048, 256, 0, stream>>>(ei, hist, rank, NE);
  k_blocksum<<<NBLK, 256, 0, stream>>>(hist, bsum, NN);
  k_scanbsum<<<1, 64, 0, stream>>>(bsum, boff, offs, NBLK, NN);
  k_scanfinal<<<NBLK, 256, 0, stream>>>(hist, boff, offs, baseo, dis, NN);
  k_fill<<<2048, 256, 0, stream>>>(ei, baseo, rank, csr, NE);
  k_zero_pool<<<(NG * H + 255) / 256, 256, 0, stream>>>(pool, cnt);

  const int GATHER_GRID = (NN + 3) / 4;   // 1 node/wave, 4 waves/block

  // layer 1: aggregate-first (A·X)·W1
  k_prescale<<<(NN * 8 + 255) / 256, 256, 0, stream>>>(x, dis, xs16, NN);
  k_gather16<<<(NN + 31) / 32, 256, 0, stream>>>(offs, csr, dis, xs16, (float2*)agg, NN);
  k_mm16<<<NN, 128, 0, stream>>>(agg, W1, b1, xbuf, NN);

  // layer 2
  k_mm128<<<(NN + 31) / 32, 256, 0, stream>>>(xbuf, W2, dis, hs8, NN);
  k_gather<true, true><<<GATHER_GRID, 256, 0, stream>>>(
      offs, csr, dis, (const ushort*)hs8, b2, (float2*)xbuf, NN);

  // layer 3
  k_mm128<<<(NN + 31) / 32, 256, 0, stream>>>(xbuf, W3, dis, hs8, NN);
  k_gather<false, false><<<GATHER_GRID, 256, 0, stream>>>(
      offs, csr, dis, (const ushort*)hs8, nullptr, (float2*)xbuf, NN);

  // pool + head
  k_pool<<<(NN + 63) / 64, 128, 0, stream>>>(xbuf, b3, batch, pool, cnt, NN);
  k_out<<<1, 256, 0, stream>>>(pool, cnt, Wlin, blin, out);
}

// Round 8
// 370.569 us; speedup vs baseline: 6.2118x; 1.2199x over previous
//
#include <hip/hip_runtime.h>

constexpr int NN = 100000;
constexpr int NE = 1600000;
constexpr int NG = 64;
constexpr int H  = 128;
constexpr int SCAN_CHUNK = 1024;
constexpr int NBLK = (NN + SCAN_CHUNK - 1) / SCAN_CHUNK;  // 98
constexpr int NPART = 8;  // XCD-private histogram partitions

typedef float v2f   __attribute__((ext_vector_type(2)));
typedef float f32x4 __attribute__((ext_vector_type(4)));
typedef short short8 __attribute__((ext_vector_type(8)));

// ---------- bf16 helpers ----------
__device__ __forceinline__ float bf_lo(unsigned v) { return __uint_as_float(v << 16); }
__device__ __forceinline__ float bf_hi(unsigned v) { return __uint_as_float(v & 0xffff0000u); }
__device__ __forceinline__ unsigned bf_pack(float a, float b) {  // RTNE
  unsigned ua = __float_as_uint(a);
  unsigned ub = __float_as_uint(b);
  ua += 0x7fffu + ((ua >> 16) & 1u);
  ub += 0x7fffu + ((ub >> 16) & 1u);
  return (ua >> 16) | (ub & 0xffff0000u);
}
__device__ __forceinline__ ushort bf1(float a) {
  unsigned u = __float_as_uint(a);
  u += 0x7fffu + ((u >> 16) & 1u);
  return (ushort)(u >> 16);
}

// ---------- CSR build ----------

__global__ void k_zero_int(int* p, int n) {
  int i = blockIdx.x * blockDim.x + threadIdx.x;
  if (i < n) p[i] = 0;
}

__global__ void k_indeg_rank(const int* __restrict__ ei, int* __restrict__ hist,
                             int* __restrict__ rank, int ne) {
  int part = blockIdx.x & (NPART - 1);
  int* h = hist + part * NN;
  int stride = gridDim.x * blockDim.x;
  for (int e = blockIdx.x * blockDim.x + threadIdx.x; e < ne; e += stride) {
    int lr = atomicAdd(&h[ei[ne + e]], 1);
    rank[e] = (lr << 3) | part;
  }
}

__global__ void k_blocksum(const int* __restrict__ hist, int* __restrict__ bsum, int n) {
  int t = threadIdx.x;
  int base = blockIdx.x * SCAN_CHUNK + t * 4;
  int s = 0;
  if (base + 3 < n) {
#pragma unroll
    for (int x = 0; x < NPART; ++x) {
      int4 v = *(const int4*)&hist[x * NN + base];
      s += v.x + v.y + v.z + v.w;
    }
  } else {
#pragma unroll
    for (int x = 0; x < NPART; ++x)
      for (int i = 0; i < 4; ++i)
        if (base + i < n) s += hist[x * NN + base + i];
  }
#pragma unroll
  for (int off = 32; off; off >>= 1) s += __shfl_down(s, off, 64);
  __shared__ int ws[4];
  if ((t & 63) == 0) ws[t >> 6] = s;
  __syncthreads();
  if (t == 0) bsum[blockIdx.x] = ws[0] + ws[1] + ws[2] + ws[3];
}

__global__ void k_scanbsum(const int* __restrict__ bsum, int* __restrict__ boff,
                           int* __restrict__ offs, int nb, int n) {
  if (threadIdx.x == 0) {
    int run = 0;
    for (int i = 0; i < nb; ++i) { int v = bsum[i]; boff[i] = run; run += v; }
    offs[n] = run;
  }
}

__global__ void k_scanfinal(const int* __restrict__ hist, const int* __restrict__ boff,
                            int* __restrict__ offs, int* __restrict__ base_out,
                            float* __restrict__ dis, int n) {
  int t = threadIdx.x;
  int base = blockIdx.x * SCAN_CHUNK + t * 4;
  int hv[NPART][4];
  int v[4];
  if (base + 3 < n) {
#pragma unroll
    for (int x = 0; x < NPART; ++x) {
      int4 q = *(const int4*)&hist[x * NN + base];
      hv[x][0] = q.x; hv[x][1] = q.y; hv[x][2] = q.z; hv[x][3] = q.w;
    }
  } else {
#pragma unroll
    for (int x = 0; x < NPART; ++x)
      for (int i = 0; i < 4; ++i)
        hv[x][i] = (base + i < n) ? hist[x * NN + base + i] : 0;
  }
#pragma unroll
  for (int i = 0; i < 4; ++i) {
    int s = 0;
#pragma unroll
    for (int x = 0; x < NPART; ++x) s += hv[x][i];
    v[i] = s;
  }
  int s = v[0] + v[1] + v[2] + v[3];

  int lane = t & 63, w = t >> 6;
  int inc = s;
#pragma unroll
  for (int off = 1; off < 64; off <<= 1) {
    int y = __shfl_up(inc, off, 64);
    if (lane >= off) inc += y;
  }
  __shared__ int wsum[4];
  if (lane == 63) wsum[w] = inc;
  __syncthreads();
  int woff = 0;
  for (int i = 0; i < w; ++i) woff += wsum[i];
  int run = woff + (inc - s) + boff[blockIdx.x];

  int starts[4];
  {
    int r = run;
#pragma unroll
    for (int i = 0; i < 4; ++i) { starts[i] = r; r += v[i]; }
  }
  if (base + 3 < n) {
    *(int4*)&offs[base] = make_int4(starts[0], starts[1], starts[2], starts[3]);
    float4 dv;
    dv.x = rsqrtf((float)(v[0] + 1));
    dv.y = rsqrtf((float)(v[1] + 1));
    dv.z = rsqrtf((float)(v[2] + 1));
    dv.w = rsqrtf((float)(v[3] + 1));
    *(float4*)&dis[base] = dv;
#pragma unroll
    for (int x = 0; x < NPART; ++x) {
      int4 bv = make_int4(starts[0], starts[1], starts[2], starts[3]);
      *(int4*)&base_out[x * NN + base] = bv;
      starts[0] += hv[x][0]; starts[1] += hv[x][1];
      starts[2] += hv[x][2]; starts[3] += hv[x][3];
    }
  } else {
#pragma unroll
    for (int i = 0; i < 4; ++i) {
      if (base + i < n) {
        offs[base + i] = starts[i];
        dis[base + i] = rsqrtf((float)(v[i] + 1));
        int acc = starts[i];
#pragma unroll
        for (int x = 0; x < NPART; ++x) {
          base_out[x * NN + base + i] = acc;
          acc += hv[x][i];
        }
      }
    }
  }
}

__global__ void k_fill(const int* __restrict__ ei, const int* __restrict__ base_out,
                       const int* __restrict__ rank, int* __restrict__ csr, int ne) {
  int stride = gridDim.x * blockDim.x;
  for (int e = blockIdx.x * blockDim.x + threadIdx.x; e < ne; e += stride) {
    int s = ei[e];
    int d = ei[ne + e];
    int r = rank[e];
    int p = r & (NPART - 1);
    csr[base_out[p * NN + d] + (r >> 3)] = s;
  }
}

// ---------- layer 1: aggregate-first (A·X)·W1 ----------

__global__ void k_prescale(const float* __restrict__ x, const float* __restrict__ dis,
                           unsigned* __restrict__ xs16, int n) {
  int i = blockIdx.x * blockDim.x + threadIdx.x;
  if (i >= n * 8) return;
  int node = i >> 3, j = i & 7;
  int f0 = 2 * j, f1 = 2 * j + 1;
  float d = dis[node];
  float a = (f0 < 10) ? x[node * 10 + f0] * d : 0.f;
  float b = (f1 < 10) ? x[node * 10 + f1] * d : 0.f;
  xs16[i] = bf_pack(a, b);
}

__global__ void k_gather16(const int* __restrict__ offs, const int* __restrict__ csr,
                           const float* __restrict__ dis, const unsigned* __restrict__ xs16,
                           float2* __restrict__ agg, int n) {
  int wid = (blockIdx.x * blockDim.x + threadIdx.x) >> 6;
  int lane = threadIdx.x & 63;
  int g = lane >> 3, sl = lane & 7;
  int node = wid * 8 + g;
  if (node >= n) return;
  unsigned self = xs16[node * 8 + sl];
  float sx = bf_lo(self), sy = bf_hi(self);
  int e = offs[node], end = offs[node + 1];
  for (; e + 1 < end; e += 2) {
    int s0 = csr[e], s1 = csr[e + 1];
    unsigned v0 = xs16[s0 * 8 + sl], v1 = xs16[s1 * 8 + sl];
    sx += bf_lo(v0) + bf_lo(v1);
    sy += bf_hi(v0) + bf_hi(v1);
  }
  if (e < end) {
    unsigned v0 = xs16[csr[e] * 8 + sl];
    sx += bf_lo(v0); sy += bf_hi(v0);
  }
  float dd = dis[node];
  float2 o; o.x = sx * dd; o.y = sy * dd;
  agg[node * 8 + sl] = o;
}

// xbuf(bf16)[node][128] = relu(agg[node][0..9] @ W1 + b1)
__global__ void k_mm16(const float* __restrict__ agg, const float* __restrict__ W1,
                       const float* __restrict__ b1, ushort* __restrict__ xbuf, int n) {
  int node = blockIdx.x;
  if (node >= n) return;
  __shared__ float as[16];
  int m = threadIdx.x;
  if (m < 16) as[m] = agg[node * 16 + m];
  __syncthreads();
  float s = 0.f;
#pragma unroll
  for (int k = 0; k < 10; ++k) s += as[k] * W1[k * H + m];
  s += b1[m];
  xbuf[node * H + m] = bf1(fmaxf(s, 0.f));
}

// ---------- W -> A-fragment pack (bf16), layout [nt][ks][lane][j] ----------
// A of mfma_16x16x32: lane holds row=(lane&15), k=(lane>>4)*8+j.
// Here A = W^T tile: row = out-feature (nt*16 + (lane&15)), k = in-feature.
__global__ void k_cvtW(const float* __restrict__ W, short* __restrict__ Wfrag) {
  int i = blockIdx.x * blockDim.x + threadIdx.x;  // 16384
  int j = i & 7, lane = (i >> 3) & 63, ks = (i >> 9) & 3, nt = i >> 11;
  int feat = nt * 16 + (lane & 15);
  int k = ks * 32 + (lane >> 4) * 8 + j;
  Wfrag[i] = (short)bf1(W[k * H + feat]);
}

// ---------- layers 2/3 dense via MFMA: hs8 = fp8( (xb @ W) * dis ) ----------
// D = A*B: A = W-tile (16 feats x 32 k), B = X^T (32 k x 16 nodes).
// D: col(lane&15)=node, row((lane>>4)*4+r)=feature -> pack 4 fp8 per u32.
__global__ void k_mm128_mfma(const short* __restrict__ xb,     // bf16 [n][128]
                             const short* __restrict__ Wfrag,  // [8][4][64][8]
                             const float* __restrict__ dis,
                             unsigned* __restrict__ hs8, int n) {
  int t = threadIdx.x;
  int lane = t & 63, w = t >> 6;
  int nbase = blockIdx.x * 64 + w * 16;
  int node = nbase + (lane & 15);
  bool valid = node < n;
  int nc = valid ? node : (n - 1);
  // B fragments (X^T), hoisted across all 8 feature-tiles
  short8 xf[4];
  const short* xrow = xb + (size_t)nc * H + (lane >> 4) * 8;
#pragma unroll
  for (int ks = 0; ks < 4; ++ks)
    xf[ks] = *(const short8*)(xrow + ks * 32);
  float d = dis[nc];
  const short8* wf = (const short8*)Wfrag;
#pragma unroll
  for (int nt = 0; nt < 8; ++nt) {
    f32x4 acc = {0.f, 0.f, 0.f, 0.f};
#pragma unroll
    for (int ks = 0; ks < 4; ++ks) {
      short8 af = wf[(nt * 4 + ks) * 64 + lane];
      acc = __builtin_amdgcn_mfma_f32_16x16x32_bf16(af, xf[ks], acc, 0, 0, 0);
    }
    if (valid) {
      int pk = __builtin_amdgcn_cvt_pk_fp8_f32(acc[0] * d, acc[1] * d, 0, false);
      pk = __builtin_amdgcn_cvt_pk_fp8_f32(acc[2] * d, acc[3] * d, pk, true);
      hs8[node * 32 + nt * 4 + (lane >> 4)] = (unsigned)pk;
    }
  }
}

// ---------- gather 128-wide: one node per wave, 2 fp8 feats per lane ----------
template <bool RELU, bool BIAS, bool OUTBF>
__global__ void k_gather(const int* __restrict__ offs, const int* __restrict__ csr,
                         const float* __restrict__ dis, const ushort* __restrict__ hs8,
                         const float* __restrict__ b, void* __restrict__ outp, int n) {
  int node = (blockIdx.x * blockDim.x + threadIdx.x) >> 6;
  int lane = threadIdx.x & 63;
  if (node >= n) return;
  v2f self = __builtin_amdgcn_cvt_pk_f32_fp8((int)hs8[node * 64 + lane], false);
  float sx = self.x, sy = self.y;
  float tx = 0.f, ty = 0.f;
  int beg = offs[node], end = offs[node + 1];
  int e = beg;
  for (; e + 7 < end; e += 8) {
    int s0 = csr[e],     s1 = csr[e + 1], s2 = csr[e + 2], s3 = csr[e + 3];
    int s4 = csr[e + 4], s5 = csr[e + 5], s6 = csr[e + 6], s7 = csr[e + 7];
    int u0 = hs8[s0 * 64 + lane], u1 = hs8[s1 * 64 + lane];
    int u2 = hs8[s2 * 64 + lane], u3 = hs8[s3 * 64 + lane];
    int u4 = hs8[s4 * 64 + lane], u5 = hs8[s5 * 64 + lane];
    int u6 = hs8[s6 * 64 + lane], u7 = hs8[s7 * 64 + lane];
    v2f v0 = __builtin_amdgcn_cvt_pk_f32_fp8(u0, false);
    v2f v1 = __builtin_amdgcn_cvt_pk_f32_fp8(u1, false);
    v2f v2 = __builtin_amdgcn_cvt_pk_f32_fp8(u2, false);
    v2f v3 = __builtin_amdgcn_cvt_pk_f32_fp8(u3, false);
    v2f v4 = __builtin_amdgcn_cvt_pk_f32_fp8(u4, false);
    v2f v5 = __builtin_amdgcn_cvt_pk_f32_fp8(u5, false);
    v2f v6 = __builtin_amdgcn_cvt_pk_f32_fp8(u6, false);
    v2f v7 = __builtin_amdgcn_cvt_pk_f32_fp8(u7, false);
    sx += v0.x + v1.x + v2.x + v3.x;
    sy += v0.y + v1.y + v2.y + v3.y;
    tx += v4.x + v5.x + v6.x + v7.x;
    ty += v4.y + v5.y + v6.y + v7.y;
  }
  for (; e < end; ++e) {
    v2f v0 = __builtin_amdgcn_cvt_pk_f32_fp8((int)hs8[csr[e] * 64 + lane], false);
    sx += v0.x; sy += v0.y;
  }
  float dd = dis[node];
  float vx = (sx + tx) * dd, vy = (sy + ty) * dd;
  if (BIAS) {
    const float2* b2 = (const float2*)b;
    float2 bb = b2[lane];
    vx += bb.x; vy += bb.y;
  }
  if (RELU) { vx = fmaxf(vx, 0.f); vy = fmaxf(vy, 0.f); }
  if (OUTBF) {
    ((unsigned*)outp)[node * 64 + lane] = bf_pack(vx, vy);
  } else {
    float2 o; o.x = vx; o.y = vy;
    ((float2*)outp)[node * 64 + lane] = o;
  }
}

// ---------- pooling / output ----------

__global__ void k_zero_pool(float* pool, float* cnt) {
  int i = blockIdx.x * blockDim.x + threadIdx.x;
  if (i < NG * H) pool[i] = 0.f;
  if (i < NG) cnt[i] = 0.f;
}

// acc is bf16 [n][128]
__global__ void k_pool(const ushort* __restrict__ acc, const float* __restrict__ b3,
                       const int* __restrict__ batch, float* pool, float* cnt, int n) {
  int m = threadIdx.x;
  int n0 = blockIdx.x * 64;
  float run = 0.f, crun = 0.f;
  int curg = -1;
  float bm = b3[m];
  for (int i = 0; i < 64; ++i) {
    int node = n0 + i;
    if (node >= n) break;
    int g = batch[node];
    if (g != curg) {
      if (curg >= 0) {
        atomicAdd(&pool[curg * H + m], run);
        if (m == 0) atomicAdd(&cnt[curg], crun);
      }
      curg = g; run = 0.f; crun = 0.f;
    }
    run += __uint_as_float((unsigned)acc[node * H + m] << 16) + bm;
    crun += 1.f;
  }
  if (curg >= 0) {
    atomicAdd(&pool[curg * H + m], run);
    if (m == 0) atomicAdd(&cnt[curg], crun);
  }
}

__global__ void k_out(const float* __restrict__ pool, const float* __restrict__ cnt,
                      const float* __restrict__ Wlin, const float* __restrict__ blin,
                      float* __restrict__ out) {
  int t = threadIdx.x;
  if (t >= NG * 3) return;
  int g = t / 3, c = t % 3;
  float invc = 1.f / fmaxf(cnt[g], 1.f);
  float s = 0.f;
  for (int m = 0; m < H; ++m) s += pool[g * H + m] * Wlin[m * 3 + c];
  out[t] = s * invc + blin[c];
}

extern "C" void kernel_launch(void* const* d_in, const int* in_sizes, int n_in,
                              void* d_out, int out_size, void* d_ws, size_t ws_size,
                              hipStream_t stream) {
  const float* x     = (const float*)d_in[0];
  const int*   ei    = (const int*)d_in[1];
  const int*   batch = (const int*)d_in[2];
  const float* W1    = (const float*)d_in[3];
  const float* b1    = (const float*)d_in[4];
  const float* W2    = (const float*)d_in[5];
  const float* b2    = (const float*)d_in[6];
  const float* W3    = (const float*)d_in[7];
  const float* b3    = (const float*)d_in[8];
  const float* Wlin  = (const float*)d_in[9];
  const float* blin  = (const float*)d_in[10];
  float* out = (float*)d_out;

  char* ws = (char*)d_ws;
  float*    dis   = (float*)ws;     ws += sizeof(float) * NN;
  unsigned* hs8   = (unsigned*)ws;  ws += (size_t)NN * H;                  // fp8
  ushort*   xbuf  = (ushort*)ws;    ws += sizeof(ushort) * (size_t)NN * H; // bf16
  short*    Wfrag = (short*)ws;     ws += sizeof(short) * 8 * 4 * 64 * 8;  // 32 KB
  unsigned* xs16  = (unsigned*)ws;  ws += sizeof(unsigned) * (size_t)NN * 8;
  float*    agg   = (float*)ws;     ws += sizeof(float) * (size_t)NN * 16;
  float*    pool  = (float*)ws;     ws += sizeof(float) * NG * H;
  float*    cnt   = (float*)ws;     ws += sizeof(float) * NG;
  int*      hist  = (int*)ws;       ws += sizeof(int) * NPART * NN;
  int*      baseo = (int*)ws;       ws += sizeof(int) * NPART * NN;
  int*      offs  = (int*)ws;       ws += sizeof(int) * (NN + 8);
  int*      rank  = (int*)ws;       ws += sizeof(int) * NE;
  int*      csr   = (int*)ws;       ws += sizeof(int) * NE;
  int*      bsum  = (int*)ws;       ws += sizeof(int) * NBLK;
  int*      boff  = (int*)ws;       ws += sizeof(int) * NBLK;

  // CSR build: XCD-partitioned histogram + rank, scan, atomic-free fill
  k_zero_int<<<(NPART * NN + 255) / 256, 256, 0, stream>>>(hist, NPART * NN);
  k_indeg_rank<<<2048, 256, 0, stream>>>(ei, hist, rank, NE);
  k_blocksum<<<NBLK, 256, 0, stream>>>(hist, bsum, NN);
  k_scanbsum<<<1, 64, 0, stream>>>(bsum, boff, offs, NBLK, NN);
  k_scanfinal<<<NBLK, 256, 0, stream>>>(hist, boff, offs, baseo, dis, NN);
  k_fill<<<2048, 256, 0, stream>>>(ei, baseo, rank, csr, NE);
  k_zero_pool<<<(NG * H + 255) / 256, 256, 0, stream>>>(pool, cnt);

  const int GATHER_GRID = (NN + 3) / 4;   // 1 node/wave, 4 waves/block
  const int MM_GRID = (NN + 63) / 64;     // 64 nodes/block (16/wave)

  // layer 1: aggregate-first (A·X)·W1
  k_prescale<<<(NN * 8 + 255) / 256, 256, 0, stream>>>(x, dis, xs16, NN);
  k_gather16<<<(NN + 31) / 32, 256, 0, stream>>>(offs, csr, dis, xs16, (float2*)agg, NN);
  k_mm16<<<NN, 128, 0, stream>>>(agg, W1, b1, xbuf, NN);

  // layer 2
  k_cvtW<<<64, 256, 0, stream>>>(W2, Wfrag);
  k_mm128_mfma<<<MM_GRID, 256, 0, stream>>>((const short*)xbuf, Wfrag, dis, hs8, NN);
  k_gather<true, true, true><<<GATHER_GRID, 256, 0, stream>>>(
      offs, csr, dis, (const ushort*)hs8, b2, xbuf, NN);

  // layer 3
  k_cvtW<<<64, 256, 0, stream>>>(W3, Wfrag);
  k_mm128_mfma<<<MM_GRID, 256, 0, stream>>>((const short*)xbuf, Wfrag, dis, hs8, NN);
  k_gather<false, false, true><<<GATHER_GRID, 256, 0, stream>>>(
      offs, csr, dis, (const ushort*)hs8, nullptr, xbuf, NN);

  // pool + head
  k_pool<<<(NN + 63) / 64, 128, 0, stream>>>(xbuf, b3, batch, pool, cnt, NN);
  k_out<<<1, 256, 0, stream>>>(pool, cnt, Wlin, blin, out);
}

// Round 9
// 338.697 us; speedup vs baseline: 6.7963x; 1.0941x over previous
//
#include <hip/hip_runtime.h>

constexpr int NN = 100000;
constexpr int NE = 1600000;
constexpr int NG = 64;
constexpr int H  = 128;
constexpr int SCAN_CHUNK = 1024;
constexpr int NBLK = (NN + SCAN_CHUNK - 1) / SCAN_CHUNK;  // 98
constexpr int NPART = 8;  // XCD-private histogram partitions

typedef float v2f   __attribute__((ext_vector_type(2)));
typedef float f32x4 __attribute__((ext_vector_type(4)));
typedef short short8 __attribute__((ext_vector_type(8)));

// ---------- bf16 helpers ----------
__device__ __forceinline__ float bf_lo(unsigned v) { return __uint_as_float(v << 16); }
__device__ __forceinline__ float bf_hi(unsigned v) { return __uint_as_float(v & 0xffff0000u); }
__device__ __forceinline__ unsigned bf_pack(float a, float b) {  // RTNE
  unsigned ua = __float_as_uint(a);
  unsigned ub = __float_as_uint(b);
  ua += 0x7fffu + ((ua >> 16) & 1u);
  ub += 0x7fffu + ((ub >> 16) & 1u);
  return (ua >> 16) | (ub & 0xffff0000u);
}
__device__ __forceinline__ ushort bf1(float a) {
  unsigned u = __float_as_uint(a);
  u += 0x7fffu + ((u >> 16) & 1u);
  return (ushort)(u >> 16);
}

// ---------- CSR build ----------

__global__ void k_zero_int(int* p, int n) {
  int i = blockIdx.x * blockDim.x + threadIdx.x;
  if (i < n) p[i] = 0;
}

__global__ void k_indeg_rank(const int* __restrict__ ei, int* __restrict__ hist,
                             int* __restrict__ rank, int ne) {
  int part = blockIdx.x & (NPART - 1);
  int* h = hist + part * NN;
  int stride = gridDim.x * blockDim.x;
  for (int e = blockIdx.x * blockDim.x + threadIdx.x; e < ne; e += stride) {
    int lr = atomicAdd(&h[ei[ne + e]], 1);
    rank[e] = (lr << 3) | part;
  }
}

__global__ void k_blocksum(const int* __restrict__ hist, int* __restrict__ bsum, int n) {
  int t = threadIdx.x;
  int base = blockIdx.x * SCAN_CHUNK + t * 4;
  int s = 0;
  if (base + 3 < n) {
#pragma unroll
    for (int x = 0; x < NPART; ++x) {
      int4 v = *(const int4*)&hist[x * NN + base];
      s += v.x + v.y + v.z + v.w;
    }
  } else {
#pragma unroll
    for (int x = 0; x < NPART; ++x)
      for (int i = 0; i < 4; ++i)
        if (base + i < n) s += hist[x * NN + base + i];
  }
#pragma unroll
  for (int off = 32; off; off >>= 1) s += __shfl_down(s, off, 64);
  __shared__ int ws[4];
  if ((t & 63) == 0) ws[t >> 6] = s;
  __syncthreads();
  if (t == 0) bsum[blockIdx.x] = ws[0] + ws[1] + ws[2] + ws[3];
}

__global__ void k_scanbsum(const int* __restrict__ bsum, int* __restrict__ boff,
                           int* __restrict__ offs, int nb, int n) {
  if (threadIdx.x == 0) {
    int run = 0;
    for (int i = 0; i < nb; ++i) { int v = bsum[i]; boff[i] = run; run += v; }
    offs[n] = run;
  }
}

__global__ void k_scanfinal(const int* __restrict__ hist, const int* __restrict__ boff,
                            int* __restrict__ offs, int* __restrict__ base_out,
                            float* __restrict__ dis, int n) {
  int t = threadIdx.x;
  int base = blockIdx.x * SCAN_CHUNK + t * 4;
  int hv[NPART][4];
  int v[4];
  if (base + 3 < n) {
#pragma unroll
    for (int x = 0; x < NPART; ++x) {
      int4 q = *(const int4*)&hist[x * NN + base];
      hv[x][0] = q.x; hv[x][1] = q.y; hv[x][2] = q.z; hv[x][3] = q.w;
    }
  } else {
#pragma unroll
    for (int x = 0; x < NPART; ++x)
      for (int i = 0; i < 4; ++i)
        hv[x][i] = (base + i < n) ? hist[x * NN + base + i] : 0;
  }
#pragma unroll
  for (int i = 0; i < 4; ++i) {
    int s = 0;
#pragma unroll
    for (int x = 0; x < NPART; ++x) s += hv[x][i];
    v[i] = s;
  }
  int s = v[0] + v[1] + v[2] + v[3];

  int lane = t & 63, w = t >> 6;
  int inc = s;
#pragma unroll
  for (int off = 1; off < 64; off <<= 1) {
    int y = __shfl_up(inc, off, 64);
    if (lane >= off) inc += y;
  }
  __shared__ int wsum[4];
  if (lane == 63) wsum[w] = inc;
  __syncthreads();
  int woff = 0;
  for (int i = 0; i < w; ++i) woff += wsum[i];
  int run = woff + (inc - s) + boff[blockIdx.x];

  int starts[4];
  {
    int r = run;
#pragma unroll
    for (int i = 0; i < 4; ++i) { starts[i] = r; r += v[i]; }
  }
  if (base + 3 < n) {
    *(int4*)&offs[base] = make_int4(starts[0], starts[1], starts[2], starts[3]);
    float4 dv;
    dv.x = rsqrtf((float)(v[0] + 1));
    dv.y = rsqrtf((float)(v[1] + 1));
    dv.z = rsqrtf((float)(v[2] + 1));
    dv.w = rsqrtf((float)(v[3] + 1));
    *(float4*)&dis[base] = dv;
#pragma unroll
    for (int x = 0; x < NPART; ++x) {
      int4 bv = make_int4(starts[0], starts[1], starts[2], starts[3]);
      *(int4*)&base_out[x * NN + base] = bv;
      starts[0] += hv[x][0]; starts[1] += hv[x][1];
      starts[2] += hv[x][2]; starts[3] += hv[x][3];
    }
  } else {
#pragma unroll
    for (int i = 0; i < 4; ++i) {
      if (base + i < n) {
        offs[base + i] = starts[i];
        dis[base + i] = rsqrtf((float)(v[i] + 1));
        int acc = starts[i];
#pragma unroll
        for (int x = 0; x < NPART; ++x) {
          base_out[x * NN + base + i] = acc;
          acc += hv[x][i];
        }
      }
    }
  }
}

__global__ void k_fill(const int* __restrict__ ei, const int* __restrict__ base_out,
                       const int* __restrict__ rank, int* __restrict__ csr, int ne) {
  int stride = gridDim.x * blockDim.x;
  for (int e = blockIdx.x * blockDim.x + threadIdx.x; e < ne; e += stride) {
    int s = ei[e];
    int d = ei[ne + e];
    int r = rank[e];
    int p = r & (NPART - 1);
    csr[base_out[p * NN + d] + (r >> 3)] = s;
  }
}

// ---------- layer 1: aggregate-first (A·X)·W1 ----------

__global__ void k_prescale(const float* __restrict__ x, const float* __restrict__ dis,
                           unsigned* __restrict__ xs16, int n) {
  int i = blockIdx.x * blockDim.x + threadIdx.x;
  if (i >= n * 8) return;
  int node = i >> 3, j = i & 7;
  int f0 = 2 * j, f1 = 2 * j + 1;
  float d = dis[node];
  float a = (f0 < 10) ? x[node * 10 + f0] * d : 0.f;
  float b = (f1 < 10) ? x[node * 10 + f1] * d : 0.f;
  xs16[i] = bf_pack(a, b);
}

__global__ void k_gather16(const int* __restrict__ offs, const int* __restrict__ csr,
                           const float* __restrict__ dis, const unsigned* __restrict__ xs16,
                           float2* __restrict__ agg, int n) {
  int wid = (blockIdx.x * blockDim.x + threadIdx.x) >> 6;
  int lane = threadIdx.x & 63;
  int g = lane >> 3, sl = lane & 7;
  int node = wid * 8 + g;
  if (node >= n) return;
  unsigned self = xs16[node * 8 + sl];
  float sx = bf_lo(self), sy = bf_hi(self);
  float tx = 0.f, ty = 0.f;
  int e = offs[node], end = offs[node + 1];
  for (; e + 3 < end; e += 4) {
    int s[4];
#pragma unroll
    for (int j = 0; j < 4; ++j) s[j] = csr[e + j];
    unsigned u[4];
#pragma unroll
    for (int j = 0; j < 4; ++j) u[j] = xs16[s[j] * 8 + sl];
    sx += bf_lo(u[0]) + bf_lo(u[1]); tx += bf_lo(u[2]) + bf_lo(u[3]);
    sy += bf_hi(u[0]) + bf_hi(u[1]); ty += bf_hi(u[2]) + bf_hi(u[3]);
  }
  for (; e < end; ++e) {
    unsigned v0 = xs16[csr[e] * 8 + sl];
    sx += bf_lo(v0); sy += bf_hi(v0);
  }
  float dd = dis[node];
  float2 o; o.x = (sx + tx) * dd; o.y = (sy + ty) * dd;
  agg[node * 8 + sl] = o;
}

// xbuf(bf16)[node][128] = relu(agg[node][0..9] @ W1 + b1)
__global__ void k_mm16(const float* __restrict__ agg, const float* __restrict__ W1,
                       const float* __restrict__ b1, ushort* __restrict__ xbuf, int n) {
  int node = blockIdx.x;
  if (node >= n) return;
  __shared__ float as[16];
  int m = threadIdx.x;
  if (m < 16) as[m] = agg[node * 16 + m];
  __syncthreads();
  float s = 0.f;
#pragma unroll
  for (int k = 0; k < 10; ++k) s += as[k] * W1[k * H + m];
  s += b1[m];
  xbuf[node * H + m] = bf1(fmaxf(s, 0.f));
}

// ---------- W -> A-fragment pack (bf16), layout [nt][ks][lane][j] ----------
__global__ void k_cvtW(const float* __restrict__ W, short* __restrict__ Wfrag) {
  int i = blockIdx.x * blockDim.x + threadIdx.x;  // 16384
  int j = i & 7, lane = (i >> 3) & 63, ks = (i >> 9) & 3, nt = i >> 11;
  int feat = nt * 16 + (lane & 15);
  int k = ks * 32 + (lane >> 4) * 8 + j;
  Wfrag[i] = (short)bf1(W[k * H + feat]);
}

// ---------- layers 2/3 dense via MFMA: hs8 = fp8( (xb @ W) * dis ) ----------
__global__ void k_mm128_mfma(const short* __restrict__ xb,     // bf16 [n][128]
                             const short* __restrict__ Wfrag,  // [8][4][64][8]
                             const float* __restrict__ dis,
                             unsigned* __restrict__ hs8, int n) {
  int t = threadIdx.x;
  int lane = t & 63, w = t >> 6;
  int nbase = blockIdx.x * 64 + w * 16;
  int node = nbase + (lane & 15);
  bool valid = node < n;
  int nc = valid ? node : (n - 1);
  short8 xf[4];
  const short* xrow = xb + (size_t)nc * H + (lane >> 4) * 8;
#pragma unroll
  for (int ks = 0; ks < 4; ++ks)
    xf[ks] = *(const short8*)(xrow + ks * 32);
  float d = dis[nc];
  const short8* wf = (const short8*)Wfrag;
#pragma unroll
  for (int nt = 0; nt < 8; ++nt) {
    f32x4 acc = {0.f, 0.f, 0.f, 0.f};
#pragma unroll
    for (int ks = 0; ks < 4; ++ks) {
      short8 af = wf[(nt * 4 + ks) * 64 + lane];
      acc = __builtin_amdgcn_mfma_f32_16x16x32_bf16(af, xf[ks], acc, 0, 0, 0);
    }
    if (valid) {
      int pk = __builtin_amdgcn_cvt_pk_fp8_f32(acc[0] * d, acc[1] * d, 0, false);
      pk = __builtin_amdgcn_cvt_pk_fp8_f32(acc[2] * d, acc[3] * d, pk, true);
      hs8[node * 32 + nt * 4 + (lane >> 4)] = (unsigned)pk;
    }
  }
}

// ---------- gather 128-wide: one node per wave, 2 fp8 feats per lane ----------
// Deep-unrolled (16/8/4/1) so a node's row-loads are all outstanding at once.
template <bool RELU, bool BIAS, bool OUTBF>
__global__ void k_gather(const int* __restrict__ offs, const int* __restrict__ csr,
                         const float* __restrict__ dis, const ushort* __restrict__ hs8,
                         const float* __restrict__ b, void* __restrict__ outp, int n) {
  int node = (blockIdx.x * blockDim.x + threadIdx.x) >> 6;
  int lane = threadIdx.x & 63;
  if (node >= n) return;
  v2f self = __builtin_amdgcn_cvt_pk_f32_fp8((int)hs8[node * 64 + lane], false);
  float sx = self.x, sy = self.y;
  float tx = 0.f, ty = 0.f;
  float px = 0.f, py = 0.f;
  float qx = 0.f, qy = 0.f;
  int e = offs[node], end = offs[node + 1];

  for (; e + 15 < end; e += 16) {
    int s[16];
#pragma unroll
    for (int j = 0; j < 16; ++j) s[j] = csr[e + j];
    int u[16];
#pragma unroll
    for (int j = 0; j < 16; ++j) u[j] = hs8[s[j] * 64 + lane];
#pragma unroll
    for (int j = 0; j < 16; j += 4) {
      v2f a0 = __builtin_amdgcn_cvt_pk_f32_fp8(u[j + 0], false);
      v2f a1 = __builtin_amdgcn_cvt_pk_f32_fp8(u[j + 1], false);
      v2f a2 = __builtin_amdgcn_cvt_pk_f32_fp8(u[j + 2], false);
      v2f a3 = __builtin_amdgcn_cvt_pk_f32_fp8(u[j + 3], false);
      sx += a0.x; sy += a0.y;
      tx += a1.x; ty += a1.y;
      px += a2.x; py += a2.y;
      qx += a3.x; qy += a3.y;
    }
  }
  if (e + 7 < end) {
    int s[8];
#pragma unroll
    for (int j = 0; j < 8; ++j) s[j] = csr[e + j];
    int u[8];
#pragma unroll
    for (int j = 0; j < 8; ++j) u[j] = hs8[s[j] * 64 + lane];
#pragma unroll
    for (int j = 0; j < 8; j += 4) {
      v2f a0 = __builtin_amdgcn_cvt_pk_f32_fp8(u[j + 0], false);
      v2f a1 = __builtin_amdgcn_cvt_pk_f32_fp8(u[j + 1], false);
      v2f a2 = __builtin_amdgcn_cvt_pk_f32_fp8(u[j + 2], false);
      v2f a3 = __builtin_amdgcn_cvt_pk_f32_fp8(u[j + 3], false);
      sx += a0.x; sy += a0.y;
      tx += a1.x; ty += a1.y;
      px += a2.x; py += a2.y;
      qx += a3.x; qy += a3.y;
    }
    e += 8;
  }
  if (e + 3 < end) {
    int s[4];
#pragma unroll
    for (int j = 0; j < 4; ++j) s[j] = csr[e + j];
    int u[4];
#pragma unroll
    for (int j = 0; j < 4; ++j) u[j] = hs8[s[j] * 64 + lane];
    v2f a0 = __builtin_amdgcn_cvt_pk_f32_fp8(u[0], false);
    v2f a1 = __builtin_amdgcn_cvt_pk_f32_fp8(u[1], false);
    v2f a2 = __builtin_amdgcn_cvt_pk_f32_fp8(u[2], false);
    v2f a3 = __builtin_amdgcn_cvt_pk_f32_fp8(u[3], false);
    sx += a0.x; sy += a0.y;
    tx += a1.x; ty += a1.y;
    px += a2.x; py += a2.y;
    qx += a3.x; qy += a3.y;
    e += 4;
  }
  for (; e < end; ++e) {
    v2f v0 = __builtin_amdgcn_cvt_pk_f32_fp8((int)hs8[csr[e] * 64 + lane], false);
    sx += v0.x; sy += v0.y;
  }
  float dd = dis[node];
  float vx = ((sx + tx) + (px + qx)) * dd;
  float vy = ((sy + ty) + (py + qy)) * dd;
  if (BIAS) {
    const float2* b2 = (const float2*)b;
    float2 bb = b2[lane];
    vx += bb.x; vy += bb.y;
  }
  if (RELU) { vx = fmaxf(vx, 0.f); vy = fmaxf(vy, 0.f); }
  if (OUTBF) {
    ((unsigned*)outp)[node * 64 + lane] = bf_pack(vx, vy);
  } else {
    float2 o; o.x = vx; o.y = vy;
    ((float2*)outp)[node * 64 + lane] = o;
  }
}

// ---------- pooling / output ----------

__global__ void k_zero_pool(float* pool, float* cnt) {
  int i = blockIdx.x * blockDim.x + threadIdx.x;
  if (i < NG * H) pool[i] = 0.f;
  if (i < NG) cnt[i] = 0.f;
}

// acc is bf16 [n][128]
__global__ void k_pool(const ushort* __restrict__ acc, const float* __restrict__ b3,
                       const int* __restrict__ batch, float* pool, float* cnt, int n) {
  int m = threadIdx.x;
  int n0 = blockIdx.x * 64;
  float run = 0.f, crun = 0.f;
  int curg = -1;
  float bm = b3[m];
  for (int i = 0; i < 64; ++i) {
    int node = n0 + i;
    if (node >= n) break;
    int g = batch[node];
    if (g != curg) {
      if (curg >= 0) {
        atomicAdd(&pool[curg * H + m], run);
        if (m == 0) atomicAdd(&cnt[curg], crun);
      }
      curg = g; run = 0.f; crun = 0.f;
    }
    run += __uint_as_float((unsigned)acc[node * H + m] << 16) + bm;
    crun += 1.f;
  }
  if (curg >= 0) {
    atomicAdd(&pool[curg * H + m], run);
    if (m == 0) atomicAdd(&cnt[curg], crun);
  }
}

__global__ void k_out(const float* __restrict__ pool, const float* __restrict__ cnt,
                      const float* __restrict__ Wlin, const float* __restrict__ blin,
                      float* __restrict__ out) {
  int t = threadIdx.x;
  if (t >= NG * 3) return;
  int g = t / 3, c = t % 3;
  float invc = 1.f / fmaxf(cnt[g], 1.f);
  float s = 0.f;
  for (int m = 0; m < H; ++m) s += pool[g * H + m] * Wlin[m * 3 + c];
  out[t] = s * invc + blin[c];
}

extern "C" void kernel_launch(void* const* d_in, const int* in_sizes, int n_in,
                              void* d_out, int out_size, void* d_ws, size_t ws_size,
                              hipStream_t stream) {
  const float* x     = (const float*)d_in[0];
  const int*   ei    = (const int*)d_in[1];
  const int*   batch = (const int*)d_in[2];
  const float* W1    = (const float*)d_in[3];
  const float* b1    = (const float*)d_in[4];
  const float* W2    = (const float*)d_in[5];
  const float* b2    = (const float*)d_in[6];
  const float* W3    = (const float*)d_in[7];
  const float* b3    = (const float*)d_in[8];
  const float* Wlin  = (const float*)d_in[9];
  const float* blin  = (const float*)d_in[10];
  float* out = (float*)d_out;

  char* ws = (char*)d_ws;
  float*    dis   = (float*)ws;     ws += sizeof(float) * NN;
  unsigned* hs8   = (unsigned*)ws;  ws += (size_t)NN * H;                  // fp8
  ushort*   xbuf  = (ushort*)ws;    ws += sizeof(ushort) * (size_t)NN * H; // bf16
  short*    Wfrag = (short*)ws;     ws += sizeof(short) * 8 * 4 * 64 * 8;  // 32 KB
  unsigned* xs16  = (unsigned*)ws;  ws += sizeof(unsigned) * (size_t)NN * 8;
  float*    agg   = (float*)ws;     ws += sizeof(float) * (size_t)NN * 16;
  float*    pool  = (float*)ws;     ws += sizeof(float) * NG * H;
  float*    cnt   = (float*)ws;     ws += sizeof(float) * NG;
  int*      hist  = (int*)ws;       ws += sizeof(int) * NPART * NN;
  int*      baseo = (int*)ws;       ws += sizeof(int) * NPART * NN;
  int*      offs  = (int*)ws;       ws += sizeof(int) * (NN + 8);
  int*      rank  = (int*)ws;       ws += sizeof(int) * NE;
  int*      csr   = (int*)ws;       ws += sizeof(int) * NE;
  int*      bsum  = (int*)ws;       ws += sizeof(int) * NBLK;
  int*      boff  = (int*)ws;       ws += sizeof(int) * NBLK;

  // CSR build: XCD-partitioned histogram + rank, scan, atomic-free fill
  k_zero_int<<<(NPART * NN + 255) / 256, 256, 0, stream>>>(hist, NPART * NN);
  k_indeg_rank<<<2048, 256, 0, stream>>>(ei, hist, rank, NE);
  k_blocksum<<<NBLK, 256, 0, stream>>>(hist, bsum, NN);
  k_scanbsum<<<1, 64, 0, stream>>>(bsum, boff, offs, NBLK, NN);
  k_scanfinal<<<NBLK, 256, 0, stream>>>(hist, boff, offs, baseo, dis, NN);
  k_fill<<<2048, 256, 0, stream>>>(ei, baseo, rank, csr, NE);
  k_zero_pool<<<(NG * H + 255) / 256, 256, 0, stream>>>(pool, cnt);

  const int GATHER_GRID = (NN + 3) / 4;   // 1 node/wave, 4 waves/block
  const int MM_GRID = (NN + 63) / 64;     // 64 nodes/block (16/wave)

  // layer 1: aggregate-first (A·X)·W1
  k_prescale<<<(NN * 8 + 255) / 256, 256, 0, stream>>>(x, dis, xs16, NN);
  k_gather16<<<(NN + 31) / 32, 256, 0, stream>>>(offs, csr, dis, xs16, (float2*)agg, NN);
  k_mm16<<<NN, 128, 0, stream>>>(agg, W1, b1, xbuf, NN);

  // layer 2
  k_cvtW<<<64, 256, 0, stream>>>(W2, Wfrag);
  k_mm128_mfma<<<MM_GRID, 256, 0, stream>>>((const short*)xbuf, Wfrag, dis, hs8, NN);
  k_gather<true, true, true><<<GATHER_GRID, 256, 0, stream>>>(
      offs, csr, dis, (const ushort*)hs8, b2, xbuf, NN);

  // layer 3
  k_cvtW<<<64, 256, 0, stream>>>(W3, Wfrag);
  k_mm128_mfma<<<MM_GRID, 256, 0, stream>>>((const short*)xbuf, Wfrag, dis, hs8, NN);
  k_gather<false, false, true><<<GATHER_GRID, 256, 0, stream>>>(
      offs, csr, dis, (const ushort*)hs8, nullptr, xbuf, NN);

  // pool + head
  k_pool<<<(NN + 63) / 64, 128, 0, stream>>>(xbuf, b3, batch, pool, cnt, NN);
  k_out<<<1, 256, 0, stream>>>(pool, cnt, Wlin, blin, out);
}

// Round 10
// 283.640 us; speedup vs baseline: 8.1155x; 1.1941x over previous
//
#include <hip/hip_runtime.h>

constexpr int NN = 100000;
constexpr int NE = 1600000;
constexpr int NG = 64;
constexpr int H  = 128;

constexpr int NB  = 392;       // dst buckets (dst >> 8, 256 nodes each)
constexpr int CAP = 5120;      // ebuf capacity per bucket (mean 4082, sigma ~64)
constexpr int P1B = 256;       // pass-1 blocks
constexpr int EPB = NE / P1B;  // 6250 edges per pass-1 block

typedef float v2f   __attribute__((ext_vector_type(2)));
typedef float f32x4 __attribute__((ext_vector_type(4)));
typedef short short8 __attribute__((ext_vector_type(8)));

// ---------- bf16 helpers ----------
__device__ __forceinline__ float bf_lo(unsigned v) { return __uint_as_float(v << 16); }
__device__ __forceinline__ float bf_hi(unsigned v) { return __uint_as_float(v & 0xffff0000u); }
__device__ __forceinline__ unsigned bf_pack(float a, float b) {  // RTNE
  unsigned ua = __float_as_uint(a);
  unsigned ub = __float_as_uint(b);
  ua += 0x7fffu + ((ua >> 16) & 1u);
  ub += 0x7fffu + ((ub >> 16) & 1u);
  return (ua >> 16) | (ub & 0xffff0000u);
}
__device__ __forceinline__ ushort bf1(float a) {
  unsigned u = __float_as_uint(a);
  u += 0x7fffu + ((u >> 16) & 1u);
  return (ushort)(u >> 16);
}

// ---------- init: pool/cnt zero + bucket cursors ----------
__global__ void k_init(float* pool, float* cnt, int* gcursor) {
  int i = blockIdx.x * blockDim.x + threadIdx.x;
  if (i < NG * H) pool[i] = 0.f;
  if (i < NG) cnt[i] = 0.f;
  if (i < NB) gcursor[i] = i * CAP;
}

// ---------- pass 1: bucket edges by dst>>8 (LDS histogram + chunk reserve) ----------
__global__ void k_bucket(const int* __restrict__ ei, int* __restrict__ gcursor,
                         unsigned* __restrict__ ebuf, int* __restrict__ dirs,
                         ushort* __restrict__ dirl) {
  __shared__ int cnt[NB];
  __shared__ int cpos[NB];
  int t = threadIdx.x, b = blockIdx.x;
  for (int j = t; j < NB; j += 256) cnt[j] = 0;
  __syncthreads();
  int e0 = b * EPB;
  for (int i = t; i < EPB; i += 256) {
    int d = ei[NE + e0 + i];
    atomicAdd(&cnt[d >> 8], 1);
  }
  __syncthreads();
  for (int j = t; j < NB; j += 256) {
    int c = cnt[j];
    int start = atomicAdd(&gcursor[j], c);
    cpos[j] = start;
    dirs[b * NB + j] = start;
    dirl[b * NB + j] = (ushort)c;
  }
  __syncthreads();
  for (int j = t; j < NB; j += 256) cnt[j] = 0;
  __syncthreads();
  for (int i = t; i < EPB; i += 256) {
    int s = ei[e0 + i];
    int d = ei[NE + e0 + i];
    int bk = d >> 8;
    int slot = cpos[bk] + atomicAdd(&cnt[bk], 1);
    ebuf[slot] = (unsigned)s | ((unsigned)(d & 255) << 17);  // src:17b | local:8b
  }
}

// ---------- tiny scan of bucket totals ----------
__global__ void k_bucketscan(const int* __restrict__ gcursor, int* __restrict__ gbase,
                             int* __restrict__ offs) {
  if (threadIdx.x == 0) {
    int run = 0;
    for (int j = 0; j < NB; ++j) {
      int tot = gcursor[j] - j * CAP;
      gbase[j] = run; run += tot;
    }
    gbase[NB] = run;
    offs[NN] = run;   // == NE
  }
}

// ---------- pass 2: per-bucket histogram/scan -> offs, dis, xs16, csr ----------
__global__ void k_csr(const unsigned* __restrict__ ebuf, const int* __restrict__ dirs,
                      const ushort* __restrict__ dirl, const int* __restrict__ gbase,
                      const float* __restrict__ x,
                      int* __restrict__ offs, float* __restrict__ dis,
                      unsigned* __restrict__ xs16, int* __restrict__ csr, int n) {
  __shared__ int histc[256];
  __shared__ int loffs[256];
  __shared__ int wps[4];
  int t = threadIdx.x, j = blockIdx.x;
  histc[t] = 0;
  __syncthreads();
  int cstart = dirs[t * NB + j];
  int clen = dirl[t * NB + j];
  for (int k = 0; k < clen; ++k) {
    unsigned u = ebuf[cstart + k];
    atomicAdd(&histc[u >> 17], 1);
  }
  __syncthreads();
  int h = histc[t];
  int inc = h;
  int lane = t & 63;
#pragma unroll
  for (int off = 1; off < 64; off <<= 1) {
    int y = __shfl_up(inc, off, 64);
    if (lane >= off) inc += y;
  }
  if (lane == 63) wps[t >> 6] = inc;
  __syncthreads();
  int woff = 0;
  for (int i = 0; i < (t >> 6); ++i) woff += wps[i];
  int excl = gbase[j] + woff + inc - h;
  loffs[t] = excl;
  int node = j * 256 + t;
  if (node < n) {
    offs[node] = excl;
    float dd = rsqrtf((float)(h + 1));
    dis[node] = dd;
    const float* xr = x + (size_t)node * 10;
#pragma unroll
    for (int q = 0; q < 8; ++q) {
      float a = (2 * q < 10) ? xr[2 * q] * dd : 0.f;
      float bb = (2 * q + 1 < 10) ? xr[2 * q + 1] * dd : 0.f;
      xs16[node * 8 + q] = bf_pack(a, bb);
    }
  }
  __syncthreads();
  for (int k = 0; k < clen; ++k) {
    unsigned u = ebuf[cstart + k];
    int src = (int)(u & 0x1FFFFu);
    int slot = atomicAdd(&loffs[u >> 17], 1);
    csr[slot] = src;
  }
}

// ---------- layer 1: gather 16-wide + dense 10x128 ----------

__global__ void k_gather16(const int* __restrict__ offs, const int* __restrict__ csr,
                           const float* __restrict__ dis, const unsigned* __restrict__ xs16,
                           float2* __restrict__ agg, int n) {
  int wid = (blockIdx.x * blockDim.x + threadIdx.x) >> 6;
  int lane = threadIdx.x & 63;
  int g = lane >> 3, sl = lane & 7;
  int node = wid * 8 + g;
  if (node >= n) return;
  unsigned self = xs16[node * 8 + sl];
  float sx = bf_lo(self), sy = bf_hi(self);
  float tx = 0.f, ty = 0.f;
  int e = offs[node], end = offs[node + 1];
  for (; e + 3 < end; e += 4) {
    int s[4];
#pragma unroll
    for (int j = 0; j < 4; ++j) s[j] = csr[e + j];
    unsigned u[4];
#pragma unroll
    for (int j = 0; j < 4; ++j) u[j] = xs16[s[j] * 8 + sl];
    sx += bf_lo(u[0]) + bf_lo(u[1]); tx += bf_lo(u[2]) + bf_lo(u[3]);
    sy += bf_hi(u[0]) + bf_hi(u[1]); ty += bf_hi(u[2]) + bf_hi(u[3]);
  }
  for (; e < end; ++e) {
    unsigned v0 = xs16[csr[e] * 8 + sl];
    sx += bf_lo(v0); sy += bf_hi(v0);
  }
  float dd = dis[node];
  float2 o; o.x = (sx + tx) * dd; o.y = (sy + ty) * dd;
  agg[node * 8 + sl] = o;
}

__global__ void k_mm16(const float* __restrict__ agg, const float* __restrict__ W1,
                       const float* __restrict__ b1, ushort* __restrict__ xbuf, int n) {
  int node = blockIdx.x;
  if (node >= n) return;
  __shared__ float as[16];
  int m = threadIdx.x;
  if (m < 16) as[m] = agg[node * 16 + m];
  __syncthreads();
  float s = 0.f;
#pragma unroll
  for (int k = 0; k < 10; ++k) s += as[k] * W1[k * H + m];
  s += b1[m];
  xbuf[node * H + m] = bf1(fmaxf(s, 0.f));
}

// ---------- W2+W3 -> A-fragment pack (bf16), layout [nt][ks][lane][j] ----------
__global__ void k_cvtW2(const float* __restrict__ W2, const float* __restrict__ W3,
                        short* __restrict__ WfragA, short* __restrict__ WfragB) {
  int i = blockIdx.x * blockDim.x + threadIdx.x;  // 32768
  const float* W = (i < 16384) ? W2 : W3;
  short* outp = (i < 16384) ? WfragA : WfragB;
  int ii = i & 16383;
  int jj = ii & 7, lane = (ii >> 3) & 63, ks = (ii >> 9) & 3, nt = ii >> 11;
  int feat = nt * 16 + (lane & 15);
  int k = ks * 32 + (lane >> 4) * 8 + jj;
  outp[ii] = (short)bf1(W[k * H + feat]);
}

// ---------- layers 2/3 dense via MFMA: hs8 = fp8( (xb @ W) * dis ) ----------
__global__ void k_mm128_mfma(const short* __restrict__ xb,     // bf16 [n][128]
                             const short* __restrict__ Wfrag,  // [8][4][64][8]
                             const float* __restrict__ dis,
                             unsigned* __restrict__ hs8, int n) {
  int t = threadIdx.x;
  int lane = t & 63, w = t >> 6;
  int nbase = blockIdx.x * 64 + w * 16;
  int node = nbase + (lane & 15);
  bool valid = node < n;
  int nc = valid ? node : (n - 1);
  short8 xf[4];
  const short* xrow = xb + (size_t)nc * H + (lane >> 4) * 8;
#pragma unroll
  for (int ks = 0; ks < 4; ++ks)
    xf[ks] = *(const short8*)(xrow + ks * 32);
  float d = dis[nc];
  const short8* wf = (const short8*)Wfrag;
#pragma unroll
  for (int nt = 0; nt < 8; ++nt) {
    f32x4 acc = {0.f, 0.f, 0.f, 0.f};
#pragma unroll
    for (int ks = 0; ks < 4; ++ks) {
      short8 af = wf[(nt * 4 + ks) * 64 + lane];
      acc = __builtin_amdgcn_mfma_f32_16x16x32_bf16(af, xf[ks], acc, 0, 0, 0);
    }
    if (valid) {
      int pk = __builtin_amdgcn_cvt_pk_fp8_f32(acc[0] * d, acc[1] * d, 0, false);
      pk = __builtin_amdgcn_cvt_pk_fp8_f32(acc[2] * d, acc[3] * d, pk, true);
      hs8[node * 32 + nt * 4 + (lane >> 4)] = (unsigned)pk;
    }
  }
}

// ---------- gather 128-wide: one node per wave, 2 fp8 feats per lane ----------
template <bool RELU, bool BIAS, bool OUTBF>
__global__ void k_gather(const int* __restrict__ offs, const int* __restrict__ csr,
                         const float* __restrict__ dis, const ushort* __restrict__ hs8,
                         const float* __restrict__ b, void* __restrict__ outp, int n) {
  int node = (blockIdx.x * blockDim.x + threadIdx.x) >> 6;
  int lane = threadIdx.x & 63;
  if (node >= n) return;
  v2f self = __builtin_amdgcn_cvt_pk_f32_fp8((int)hs8[node * 64 + lane], false);
  float sx = self.x, sy = self.y;
  float tx = 0.f, ty = 0.f;
  float px = 0.f, py = 0.f;
  float qx = 0.f, qy = 0.f;
  int e = offs[node], end = offs[node + 1];

  for (; e + 15 < end; e += 16) {
    int s[16];
#pragma unroll
    for (int j = 0; j < 16; ++j) s[j] = csr[e + j];
    int u[16];
#pragma unroll
    for (int j = 0; j < 16; ++j) u[j] = hs8[s[j] * 64 + lane];
#pragma unroll
    for (int j = 0; j < 16; j += 4) {
      v2f a0 = __builtin_amdgcn_cvt_pk_f32_fp8(u[j + 0], false);
      v2f a1 = __builtin_amdgcn_cvt_pk_f32_fp8(u[j + 1], false);
      v2f a2 = __builtin_amdgcn_cvt_pk_f32_fp8(u[j + 2], false);
      v2f a3 = __builtin_amdgcn_cvt_pk_f32_fp8(u[j + 3], false);
      sx += a0.x; sy += a0.y;
      tx += a1.x; ty += a1.y;
      px += a2.x; py += a2.y;
      qx += a3.x; qy += a3.y;
    }
  }
  if (e + 7 < end) {
    int s[8];
#pragma unroll
    for (int j = 0; j < 8; ++j) s[j] = csr[e + j];
    int u[8];
#pragma unroll
    for (int j = 0; j < 8; ++j) u[j] = hs8[s[j] * 64 + lane];
#pragma unroll
    for (int j = 0; j < 8; j += 4) {
      v2f a0 = __builtin_amdgcn_cvt_pk_f32_fp8(u[j + 0], false);
      v2f a1 = __builtin_amdgcn_cvt_pk_f32_fp8(u[j + 1], false);
      v2f a2 = __builtin_amdgcn_cvt_pk_f32_fp8(u[j + 2], false);
      v2f a3 = __builtin_amdgcn_cvt_pk_f32_fp8(u[j + 3], false);
      sx += a0.x; sy += a0.y;
      tx += a1.x; ty += a1.y;
      px += a2.x; py += a2.y;
      qx += a3.x; qy += a3.y;
    }
    e += 8;
  }
  if (e + 3 < end) {
    int s[4];
#pragma unroll
    for (int j = 0; j < 4; ++j) s[j] = csr[e + j];
    int u[4];
#pragma unroll
    for (int j = 0; j < 4; ++j) u[j] = hs8[s[j] * 64 + lane];
    v2f a0 = __builtin_amdgcn_cvt_pk_f32_fp8(u[0], false);
    v2f a1 = __builtin_amdgcn_cvt_pk_f32_fp8(u[1], false);
    v2f a2 = __builtin_amdgcn_cvt_pk_f32_fp8(u[2], false);
    v2f a3 = __builtin_amdgcn_cvt_pk_f32_fp8(u[3], false);
    sx += a0.x; sy += a0.y;
    tx += a1.x; ty += a1.y;
    px += a2.x; py += a2.y;
    qx += a3.x; qy += a3.y;
    e += 4;
  }
  for (; e < end; ++e) {
    v2f v0 = __builtin_amdgcn_cvt_pk_f32_fp8((int)hs8[csr[e] * 64 + lane], false);
    sx += v0.x; sy += v0.y;
  }
  float dd = dis[node];
  float vx = ((sx + tx) + (px + qx)) * dd;
  float vy = ((sy + ty) + (py + qy)) * dd;
  if (BIAS) {
    const float2* b2 = (const float2*)b;
    float2 bb = b2[lane];
    vx += bb.x; vy += bb.y;
  }
  if (RELU) { vx = fmaxf(vx, 0.f); vy = fmaxf(vy, 0.f); }
  if (OUTBF) {
    ((unsigned*)outp)[node * 64 + lane] = bf_pack(vx, vy);
  } else {
    float2 o; o.x = vx; o.y = vy;
    ((float2*)outp)[node * 64 + lane] = o;
  }
}

// ---------- pooling / output ----------

// acc is bf16 [n][128]
__global__ void k_pool(const ushort* __restrict__ acc, const float* __restrict__ b3,
                       const int* __restrict__ batch, float* pool, float* cnt, int n) {
  int m = threadIdx.x;
  int n0 = blockIdx.x * 64;
  float run = 0.f, crun = 0.f;
  int curg = -1;
  float bm = b3[m];
  for (int i = 0; i < 64; ++i) {
    int node = n0 + i;
    if (node >= n) break;
    int g = batch[node];
    if (g != curg) {
      if (curg >= 0) {
        atomicAdd(&pool[curg * H + m], run);
        if (m == 0) atomicAdd(&cnt[curg], crun);
      }
      curg = g; run = 0.f; crun = 0.f;
    }
    run += __uint_as_float((unsigned)acc[node * H + m] << 16) + bm;
    crun += 1.f;
  }
  if (curg >= 0) {
    atomicAdd(&pool[curg * H + m], run);
    if (m == 0) atomicAdd(&cnt[curg], crun);
  }
}

__global__ void k_out(const float* __restrict__ pool, const float* __restrict__ cnt,
                      const float* __restrict__ Wlin, const float* __restrict__ blin,
                      float* __restrict__ out) {
  int t = threadIdx.x;
  if (t >= NG * 3) return;
  int g = t / 3, c = t % 3;
  float invc = 1.f / fmaxf(cnt[g], 1.f);
  float s = 0.f;
  for (int m = 0; m < H; ++m) s += pool[g * H + m] * Wlin[m * 3 + c];
  out[t] = s * invc + blin[c];
}

extern "C" void kernel_launch(void* const* d_in, const int* in_sizes, int n_in,
                              void* d_out, int out_size, void* d_ws, size_t ws_size,
                              hipStream_t stream) {
  const float* x     = (const float*)d_in[0];
  const int*   ei    = (const int*)d_in[1];
  const int*   batch = (const int*)d_in[2];
  const float* W1    = (const float*)d_in[3];
  const float* b1    = (const float*)d_in[4];
  const float* W2    = (const float*)d_in[5];
  const float* b2    = (const float*)d_in[6];
  const float* W3    = (const float*)d_in[7];
  const float* b3    = (const float*)d_in[8];
  const float* Wlin  = (const float*)d_in[9];
  const float* blin  = (const float*)d_in[10];
  float* out = (float*)d_out;

  char* ws = (char*)d_ws;
  float*    dis    = (float*)ws;     ws += sizeof(float) * NN;
  unsigned* hs8    = (unsigned*)ws;  ws += (size_t)NN * H;                  // fp8
  ushort*   xbuf   = (ushort*)ws;    ws += sizeof(ushort) * (size_t)NN * H; // bf16
  short*    WfragA = (short*)ws;     ws += sizeof(short) * 16384;
  short*    WfragB = (short*)ws;     ws += sizeof(short) * 16384;
  unsigned* xs16   = (unsigned*)ws;  ws += sizeof(unsigned) * (size_t)NN * 8;
  float*    agg    = (float*)ws;     ws += sizeof(float) * (size_t)NN * 16;
  float*    pool   = (float*)ws;     ws += sizeof(float) * NG * H;
  float*    cnt    = (float*)ws;     ws += sizeof(float) * NG;
  int*      offs   = (int*)ws;       ws += sizeof(int) * (NN + 8);
  int*      csr    = (int*)ws;       ws += sizeof(int) * NE;
  unsigned* ebuf   = (unsigned*)ws;  ws += sizeof(unsigned) * (size_t)NB * CAP;
  int*      dirs   = (int*)ws;       ws += sizeof(int) * P1B * NB;
  ushort*   dirl   = (ushort*)ws;    ws += sizeof(ushort) * P1B * NB;
  int*      gcur   = (int*)ws;       ws += sizeof(int) * NB;
  int*      gbase  = (int*)ws;       ws += sizeof(int) * (NB + 1);

  // CSR build: LDS-bucketed counting sort (no fine-grained device atomics)
  k_init<<<32, 256, 0, stream>>>(pool, cnt, gcur);
  k_bucket<<<P1B, 256, 0, stream>>>(ei, gcur, ebuf, dirs, dirl);
  k_bucketscan<<<1, 64, 0, stream>>>(gcur, gbase, offs);
  k_csr<<<NB, 256, 0, stream>>>(ebuf, dirs, dirl, gbase, x, offs, dis, xs16, csr, NN);
  k_cvtW2<<<128, 256, 0, stream>>>(W2, W3, WfragA, WfragB);

  const int GATHER_GRID = (NN + 3) / 4;   // 1 node/wave, 4 waves/block
  const int MM_GRID = (NN + 63) / 64;     // 64 nodes/block (16/wave)

  // layer 1: aggregate-first (A·X)·W1
  k_gather16<<<(NN + 31) / 32, 256, 0, stream>>>(offs, csr, dis, xs16, (float2*)agg, NN);
  k_mm16<<<NN, 128, 0, stream>>>(agg, W1, b1, xbuf, NN);

  // layer 2
  k_mm128_mfma<<<MM_GRID, 256, 0, stream>>>((const short*)xbuf, WfragA, dis, hs8, NN);
  k_gather<true, true, true><<<GATHER_GRID, 256, 0, stream>>>(
      offs, csr, dis, (const ushort*)hs8, b2, xbuf, NN);

  // layer 3
  k_mm128_mfma<<<MM_GRID, 256, 0, stream>>>((const short*)xbuf, WfragB, dis, hs8, NN);
  k_gather<false, false, true><<<GATHER_GRID, 256, 0, stream>>>(
      offs, csr, dis, (const ushort*)hs8, nullptr, xbuf, NN);

  // pool + head
  k_pool<<<(NN + 63) / 64, 128, 0, stream>>>(xbuf, b3, batch, pool, cnt, NN);
  k_out<<<1, 256, 0, stream>>>(pool, cnt, Wlin, blin, out);
}

// Round 11
// 259.743 us; speedup vs baseline: 8.8622x; 1.0920x over previous
//
#include <hip/hip_runtime.h>

constexpr int NN = 100000;
constexpr int NE = 1600000;
constexpr int NG = 64;
constexpr int H  = 128;

constexpr int NB  = 392;       // dst buckets (dst >> 8, 256 nodes each)
constexpr int CAP = 5120;      // ebuf capacity per bucket (mean 4082, sigma ~64)
constexpr int P1B = 256;       // pass-1 blocks
constexpr int EPB = NE / P1B;  // 6250 edges per pass-1 block

typedef float v2f   __attribute__((ext_vector_type(2)));
typedef float f32x4 __attribute__((ext_vector_type(4)));
typedef short short8 __attribute__((ext_vector_type(8)));

// ---------- bf16 helpers ----------
__device__ __forceinline__ float bf_lo(unsigned v) { return __uint_as_float(v << 16); }
__device__ __forceinline__ float bf_hi(unsigned v) { return __uint_as_float(v & 0xffff0000u); }
__device__ __forceinline__ unsigned bf_pack(float a, float b) {  // RTNE
  unsigned ua = __float_as_uint(a);
  unsigned ub = __float_as_uint(b);
  ua += 0x7fffu + ((ua >> 16) & 1u);
  ub += 0x7fffu + ((ub >> 16) & 1u);
  return (ua >> 16) | (ub & 0xffff0000u);
}
__device__ __forceinline__ ushort bf1(float a) {
  unsigned u = __float_as_uint(a);
  u += 0x7fffu + ((u >> 16) & 1u);
  return (ushort)(u >> 16);
}

// ---------- init: pool/cnt zero + bucket cursors ----------
__global__ void k_init(float* pool, float* cnt, int* gcursor) {
  int i = blockIdx.x * blockDim.x + threadIdx.x;
  if (i < NG * H) pool[i] = 0.f;
  if (i < NG) cnt[i] = 0.f;
  if (i < NB) gcursor[i] = i * CAP;
}

// ---------- pass 1: bucket edges by dst>>8 (LDS histogram + chunk reserve) ----------
__global__ void k_bucket(const int* __restrict__ ei, int* __restrict__ gcursor,
                         unsigned* __restrict__ ebuf, int* __restrict__ dirs,
                         ushort* __restrict__ dirl) {
  __shared__ int cnt[NB];
  __shared__ int cpos[NB];
  int t = threadIdx.x, b = blockIdx.x;
  for (int j = t; j < NB; j += 256) cnt[j] = 0;
  __syncthreads();
  int e0 = b * EPB;
  for (int i = t; i < EPB; i += 256) {
    int d = ei[NE + e0 + i];
    atomicAdd(&cnt[d >> 8], 1);
  }
  __syncthreads();
  for (int j = t; j < NB; j += 256) {
    int c = cnt[j];
    int start = atomicAdd(&gcursor[j], c);
    cpos[j] = start;
    dirs[b * NB + j] = start;
    dirl[b * NB + j] = (ushort)c;
  }
  __syncthreads();
  for (int j = t; j < NB; j += 256) cnt[j] = 0;
  __syncthreads();
  for (int i = t; i < EPB; i += 256) {
    int s = ei[e0 + i];
    int d = ei[NE + e0 + i];
    int bk = d >> 8;
    int slot = cpos[bk] + atomicAdd(&cnt[bk], 1);
    ebuf[slot] = (unsigned)s | ((unsigned)(d & 255) << 17);  // src:17b | local:8b
  }
}

// ---------- tiny scan of bucket totals ----------
__global__ void k_bucketscan(const int* __restrict__ gcursor, int* __restrict__ gbase,
                             int* __restrict__ offs) {
  if (threadIdx.x == 0) {
    int run = 0;
    for (int j = 0; j < NB; ++j) {
      int tot = gcursor[j] - j * CAP;
      gbase[j] = run; run += tot;
    }
    gbase[NB] = run;
    offs[NN] = run;   // == NE
  }
}

// ---------- pass 2: per-bucket histogram/scan -> offs, dis, xs16, csr ----------
__global__ void k_csr(const unsigned* __restrict__ ebuf, const int* __restrict__ dirs,
                      const ushort* __restrict__ dirl, const int* __restrict__ gbase,
                      const float* __restrict__ x,
                      int* __restrict__ offs, float* __restrict__ dis,
                      unsigned* __restrict__ xs16, int* __restrict__ csr, int n) {
  __shared__ int histc[256];
  __shared__ int loffs[256];
  __shared__ int wps[4];
  int t = threadIdx.x, j = blockIdx.x;
  histc[t] = 0;
  __syncthreads();
  int cstart = dirs[t * NB + j];
  int clen = dirl[t * NB + j];
  for (int k = 0; k < clen; ++k) {
    unsigned u = ebuf[cstart + k];
    atomicAdd(&histc[u >> 17], 1);
  }
  __syncthreads();
  int h = histc[t];
  int inc = h;
  int lane = t & 63;
#pragma unroll
  for (int off = 1; off < 64; off <<= 1) {
    int y = __shfl_up(inc, off, 64);
    if (lane >= off) inc += y;
  }
  if (lane == 63) wps[t >> 6] = inc;
  __syncthreads();
  int woff = 0;
  for (int i = 0; i < (t >> 6); ++i) woff += wps[i];
  int excl = gbase[j] + woff + inc - h;
  loffs[t] = excl;
  int node = j * 256 + t;
  if (node < n) {
    offs[node] = excl;
    float dd = rsqrtf((float)(h + 1));
    dis[node] = dd;
    const float* xr = x + (size_t)node * 10;
#pragma unroll
    for (int q = 0; q < 8; ++q) {
      float a = (2 * q < 10) ? xr[2 * q] * dd : 0.f;
      float bb = (2 * q + 1 < 10) ? xr[2 * q + 1] * dd : 0.f;
      xs16[node * 8 + q] = bf_pack(a, bb);
    }
  }
  __syncthreads();
  for (int k = 0; k < clen; ++k) {
    unsigned u = ebuf[cstart + k];
    int src = (int)(u & 0x1FFFFu);
    int slot = atomicAdd(&loffs[u >> 17], 1);
    csr[slot] = src;
  }
}

// ---------- layer 1: gather 16-wide + dense 10x128 ----------

__global__ void k_gather16(const int* __restrict__ offs, const int* __restrict__ csr,
                           const float* __restrict__ dis, const unsigned* __restrict__ xs16,
                           float2* __restrict__ agg, int n) {
  int wid = (blockIdx.x * blockDim.x + threadIdx.x) >> 6;
  int lane = threadIdx.x & 63;
  int g = lane >> 3, sl = lane & 7;
  int node = wid * 8 + g;
  if (node >= n) return;
  unsigned self = xs16[node * 8 + sl];
  float sx = bf_lo(self), sy = bf_hi(self);
  float tx = 0.f, ty = 0.f;
  int e = offs[node], end = offs[node + 1];
  for (; e + 3 < end; e += 4) {
    int s[4];
#pragma unroll
    for (int j = 0; j < 4; ++j) s[j] = csr[e + j];
    unsigned u[4];
#pragma unroll
    for (int j = 0; j < 4; ++j) u[j] = xs16[s[j] * 8 + sl];
    sx += bf_lo(u[0]) + bf_lo(u[1]); tx += bf_lo(u[2]) + bf_lo(u[3]);
    sy += bf_hi(u[0]) + bf_hi(u[1]); ty += bf_hi(u[2]) + bf_hi(u[3]);
  }
  for (; e < end; ++e) {
    unsigned v0 = xs16[csr[e] * 8 + sl];
    sx += bf_lo(v0); sy += bf_hi(v0);
  }
  float dd = dis[node];
  float2 o; o.x = (sx + tx) * dd; o.y = (sy + ty) * dd;
  agg[node * 8 + sl] = o;
}

__global__ void k_mm16(const float* __restrict__ agg, const float* __restrict__ W1,
                       const float* __restrict__ b1, ushort* __restrict__ xbuf, int n) {
  int node = blockIdx.x;
  if (node >= n) return;
  __shared__ float as[16];
  int m = threadIdx.x;
  if (m < 16) as[m] = agg[node * 16 + m];
  __syncthreads();
  float s = 0.f;
#pragma unroll
  for (int k = 0; k < 10; ++k) s += as[k] * W1[k * H + m];
  s += b1[m];
  xbuf[node * H + m] = bf1(fmaxf(s, 0.f));
}

// ---------- W2+W3 -> A-fragment pack (bf16), layout [nt][ks][lane][j] ----------
__global__ void k_cvtW2(const float* __restrict__ W2, const float* __restrict__ W3,
                        short* __restrict__ WfragA, short* __restrict__ WfragB) {
  int i = blockIdx.x * blockDim.x + threadIdx.x;  // 32768
  const float* W = (i < 16384) ? W2 : W3;
  short* outp = (i < 16384) ? WfragA : WfragB;
  int ii = i & 16383;
  int jj = ii & 7, lane = (ii >> 3) & 63, ks = (ii >> 9) & 3, nt = ii >> 11;
  int feat = nt * 16 + (lane & 15);
  int k = ks * 32 + (lane >> 4) * 8 + jj;
  outp[ii] = (short)bf1(W[k * H + feat]);
}

// ---------- layers 2/3 dense via MFMA: hs8 = fp8( (xb @ W) * dis ) ----------
__global__ void k_mm128_mfma(const short* __restrict__ xb,     // bf16 [n][128]
                             const short* __restrict__ Wfrag,  // [8][4][64][8]
                             const float* __restrict__ dis,
                             unsigned* __restrict__ hs8, int n) {
  int t = threadIdx.x;
  int lane = t & 63, w = t >> 6;
  int nbase = blockIdx.x * 64 + w * 16;
  int node = nbase + (lane & 15);
  bool valid = node < n;
  int nc = valid ? node : (n - 1);
  short8 xf[4];
  const short* xrow = xb + (size_t)nc * H + (lane >> 4) * 8;
#pragma unroll
  for (int ks = 0; ks < 4; ++ks)
    xf[ks] = *(const short8*)(xrow + ks * 32);
  float d = dis[nc];
  const short8* wf = (const short8*)Wfrag;
#pragma unroll
  for (int nt = 0; nt < 8; ++nt) {
    f32x4 acc = {0.f, 0.f, 0.f, 0.f};
#pragma unroll
    for (int ks = 0; ks < 4; ++ks) {
      short8 af = wf[(nt * 4 + ks) * 64 + lane];
      acc = __builtin_amdgcn_mfma_f32_16x16x32_bf16(af, xf[ks], acc, 0, 0, 0);
    }
    if (valid) {
      int pk = __builtin_amdgcn_cvt_pk_fp8_f32(acc[0] * d, acc[1] * d, 0, false);
      pk = __builtin_amdgcn_cvt_pk_fp8_f32(acc[2] * d, acc[3] * d, pk, true);
      hs8[node * 32 + nt * 4 + (lane >> 4)] = (unsigned)pk;
    }
  }
}

// ---------- gather 128-wide: one node per wave, 2 fp8 feats per lane ----------
// node/e/csr indices are wave-uniform: readfirstlane forces them onto the
// scalar pipe (s_load for csr batches, saddr-form row loads, SALU bases).
template <bool RELU, bool BIAS, bool OUTBF>
__global__ void k_gather(const int* __restrict__ offs, const int* __restrict__ csr,
                         const float* __restrict__ dis, const ushort* __restrict__ hs8,
                         const float* __restrict__ b, void* __restrict__ outp, int n) {
  int node = (blockIdx.x * blockDim.x + threadIdx.x) >> 6;
  node = __builtin_amdgcn_readfirstlane(node);
  int lane = threadIdx.x & 63;
  if (node >= n) return;
  v2f self = __builtin_amdgcn_cvt_pk_f32_fp8((int)hs8[(size_t)node * 64 + lane], false);
  float sx = self.x, sy = self.y;
  float tx = 0.f, ty = 0.f;
  float px = 0.f, py = 0.f;
  float qx = 0.f, qy = 0.f;
  int e = __builtin_amdgcn_readfirstlane(offs[node]);
  int end = __builtin_amdgcn_readfirstlane(offs[node + 1]);

  for (; e + 15 < end; e += 16) {
    int s[16];
#pragma unroll
    for (int j = 0; j < 16; ++j) s[j] = __builtin_amdgcn_readfirstlane(csr[e + j]);
    int u[16];
#pragma unroll
    for (int j = 0; j < 16; ++j) u[j] = (hs8 + (size_t)s[j] * 64)[lane];
#pragma unroll
    for (int j = 0; j < 16; j += 4) {
      v2f a0 = __builtin_amdgcn_cvt_pk_f32_fp8(u[j + 0], false);
      v2f a1 = __builtin_amdgcn_cvt_pk_f32_fp8(u[j + 1], false);
      v2f a2 = __builtin_amdgcn_cvt_pk_f32_fp8(u[j + 2], false);
      v2f a3 = __builtin_amdgcn_cvt_pk_f32_fp8(u[j + 3], false);
      sx += a0.x; sy += a0.y;
      tx += a1.x; ty += a1.y;
      px += a2.x; py += a2.y;
      qx += a3.x; qy += a3.y;
    }
  }
  if (e + 7 < end) {
    int s[8];
#pragma unroll
    for (int j = 0; j < 8; ++j) s[j] = __builtin_amdgcn_readfirstlane(csr[e + j]);
    int u[8];
#pragma unroll
    for (int j = 0; j < 8; ++j) u[j] = (hs8 + (size_t)s[j] * 64)[lane];
#pragma unroll
    for (int j = 0; j < 8; j += 4) {
      v2f a0 = __builtin_amdgcn_cvt_pk_f32_fp8(u[j + 0], false);
      v2f a1 = __builtin_amdgcn_cvt_pk_f32_fp8(u[j + 1], false);
      v2f a2 = __builtin_amdgcn_cvt_pk_f32_fp8(u[j + 2], false);
      v2f a3 = __builtin_amdgcn_cvt_pk_f32_fp8(u[j + 3], false);
      sx += a0.x; sy += a0.y;
      tx += a1.x; ty += a1.y;
      px += a2.x; py += a2.y;
      qx += a3.x; qy += a3.y;
    }
    e += 8;
  }
  if (e + 3 < end) {
    int s[4];
#pragma unroll
    for (int j = 0; j < 4; ++j) s[j] = __builtin_amdgcn_readfirstlane(csr[e + j]);
    int u[4];
#pragma unroll
    for (int j = 0; j < 4; ++j) u[j] = (hs8 + (size_t)s[j] * 64)[lane];
    v2f a0 = __builtin_amdgcn_cvt_pk_f32_fp8(u[0], false);
    v2f a1 = __builtin_amdgcn_cvt_pk_f32_fp8(u[1], false);
    v2f a2 = __builtin_amdgcn_cvt_pk_f32_fp8(u[2], false);
    v2f a3 = __builtin_amdgcn_cvt_pk_f32_fp8(u[3], false);
    sx += a0.x; sy += a0.y;
    tx += a1.x; ty += a1.y;
    px += a2.x; py += a2.y;
    qx += a3.x; qy += a3.y;
    e += 4;
  }
  for (; e < end; ++e) {
    int s0 = __builtin_amdgcn_readfirstlane(csr[e]);
    v2f v0 = __builtin_amdgcn_cvt_pk_f32_fp8((int)(hs8 + (size_t)s0 * 64)[lane], false);
    sx += v0.x; sy += v0.y;
  }
  float dd = dis[node];
  float vx = ((sx + tx) + (px + qx)) * dd;
  float vy = ((sy + ty) + (py + qy)) * dd;
  if (BIAS) {
    const float2* b2 = (const float2*)b;
    float2 bb = b2[lane];
    vx += bb.x; vy += bb.y;
  }
  if (RELU) { vx = fmaxf(vx, 0.f); vy = fmaxf(vy, 0.f); }
  if (OUTBF) {
    ((unsigned*)outp)[(size_t)node * 64 + lane] = bf_pack(vx, vy);
  } else {
    float2 o; o.x = vx; o.y = vy;
    ((float2*)outp)[(size_t)node * 64 + lane] = o;
  }
}

// ---------- pooling / output ----------

// acc is bf16 [n][128]
__global__ void k_pool(const ushort* __restrict__ acc, const float* __restrict__ b3,
                       const int* __restrict__ batch, float* pool, float* cnt, int n) {
  int m = threadIdx.x;
  int n0 = blockIdx.x * 64;
  float run = 0.f, crun = 0.f;
  int curg = -1;
  float bm = b3[m];
  for (int i = 0; i < 64; ++i) {
    int node = n0 + i;
    if (node >= n) break;
    int g = batch[node];
    if (g != curg) {
      if (curg >= 0) {
        atomicAdd(&pool[curg * H + m], run);
        if (m == 0) atomicAdd(&cnt[curg], crun);
      }
      curg = g; run = 0.f; crun = 0.f;
    }
    run += __uint_as_float((unsigned)acc[node * H + m] << 16) + bm;
    crun += 1.f;
  }
  if (curg >= 0) {
    atomicAdd(&pool[curg * H + m], run);
    if (m == 0) atomicAdd(&cnt[curg], crun);
  }
}

__global__ void k_out(const float* __restrict__ pool, const float* __restrict__ cnt,
                      const float* __restrict__ Wlin, const float* __restrict__ blin,
                      float* __restrict__ out) {
  int t = threadIdx.x;
  if (t >= NG * 3) return;
  int g = t / 3, c = t % 3;
  float invc = 1.f / fmaxf(cnt[g], 1.f);
  float s = 0.f;
  for (int m = 0; m < H; ++m) s += pool[g * H + m] * Wlin[m * 3 + c];
  out[t] = s * invc + blin[c];
}

extern "C" void kernel_launch(void* const* d_in, const int* in_sizes, int n_in,
                              void* d_out, int out_size, void* d_ws, size_t ws_size,
                              hipStream_t stream) {
  const float* x     = (const float*)d_in[0];
  const int*   ei    = (const int*)d_in[1];
  const int*   batch = (const int*)d_in[2];
  const float* W1    = (const float*)d_in[3];
  const float* b1    = (const float*)d_in[4];
  const float* W2    = (const float*)d_in[5];
  const float* b2    = (const float*)d_in[6];
  const float* W3    = (const float*)d_in[7];
  const float* b3    = (const float*)d_in[8];
  const float* Wlin  = (const float*)d_in[9];
  const float* blin  = (const float*)d_in[10];
  float* out = (float*)d_out;

  char* ws = (char*)d_ws;
  float*    dis    = (float*)ws;     ws += sizeof(float) * NN;
  unsigned* hs8    = (unsigned*)ws;  ws += (size_t)NN * H;                  // fp8
  ushort*   xbuf   = (ushort*)ws;    ws += sizeof(ushort) * (size_t)NN * H; // bf16
  short*    WfragA = (short*)ws;     ws += sizeof(short) * 16384;
  short*    WfragB = (short*)ws;     ws += sizeof(short) * 16384;
  unsigned* xs16   = (unsigned*)ws;  ws += sizeof(unsigned) * (size_t)NN * 8;
  float*    agg    = (float*)ws;     ws += sizeof(float) * (size_t)NN * 16;
  float*    pool   = (float*)ws;     ws += sizeof(float) * NG * H;
  float*    cnt    = (float*)ws;     ws += sizeof(float) * NG;
  int*      offs   = (int*)ws;       ws += sizeof(int) * (NN + 8);
  int*      csr    = (int*)ws;       ws += sizeof(int) * NE;
  unsigned* ebuf   = (unsigned*)ws;  ws += sizeof(unsigned) * (size_t)NB * CAP;
  int*      dirs   = (int*)ws;       ws += sizeof(int) * P1B * NB;
  ushort*   dirl   = (ushort*)ws;    ws += sizeof(ushort) * P1B * NB;
  int*      gcur   = (int*)ws;       ws += sizeof(int) * NB;
  int*      gbase  = (int*)ws;       ws += sizeof(int) * (NB + 1);

  // CSR build: LDS-bucketed counting sort (no fine-grained device atomics)
  k_init<<<32, 256, 0, stream>>>(pool, cnt, gcur);
  k_bucket<<<P1B, 256, 0, stream>>>(ei, gcur, ebuf, dirs, dirl);
  k_bucketscan<<<1, 64, 0, stream>>>(gcur, gbase, offs);
  k_csr<<<NB, 256, 0, stream>>>(ebuf, dirs, dirl, gbase, x, offs, dis, xs16, csr, NN);
  k_cvtW2<<<128, 256, 0, stream>>>(W2, W3, WfragA, WfragB);

  const int GATHER_GRID = (NN + 3) / 4;   // 1 node/wave, 4 waves/block
  const int MM_GRID = (NN + 63) / 64;     // 64 nodes/block (16/wave)

  // layer 1: aggregate-first (A·X)·W1
  k_gather16<<<(NN + 31) / 32, 256, 0, stream>>>(offs, csr, dis, xs16, (float2*)agg, NN);
  k_mm16<<<NN, 128, 0, stream>>>(agg, W1, b1, xbuf, NN);

  // layer 2
  k_mm128_mfma<<<MM_GRID, 256, 0, stream>>>((const short*)xbuf, WfragA, dis, hs8, NN);
  k_gather<true, true, true><<<GATHER_GRID, 256, 0, stream>>>(
      offs, csr, dis, (const ushort*)hs8, b2, xbuf, NN);

  // layer 3
  k_mm128_mfma<<<MM_GRID, 256, 0, stream>>>((const short*)xbuf, WfragB, dis, hs8, NN);
  k_gather<false, false, true><<<GATHER_GRID, 256, 0, stream>>>(
      offs, csr, dis, (const ushort*)hs8, nullptr, xbuf, NN);

  // pool + head
  k_pool<<<(NN + 63) / 64, 128, 0, stream>>>(xbuf, b3, batch, pool, cnt, NN);
  k_out<<<1, 256, 0, stream>>>(pool, cnt, Wlin, blin, out);
}